// Round 17
// baseline (293.350 us; speedup 1.0000x reference)
//
#include <hip/hip_runtime.h>
#include <hip/hip_bf16.h>
#include <math.h>

#define BB 4
#define NN 4096
#define FEAT 64
#define HID 128
#define KNN 16
#define GS 258
#define CIN 66

typedef __attribute__((ext_vector_type(8))) short bf16x8;
typedef __attribute__((ext_vector_type(4))) float f32x4;
#define MFMA_B16(a, b, c) __builtin_amdgcn_mfma_f32_16x16x32_bf16(a, b, c, 0, 0, 0)
#define SWZ(r) ((((r) & 7) << 4) ^ (((r) & 8) << 2))

__device__ __forceinline__ short f2b(float f) {
    __hip_bfloat16 h = __float2bfloat16(f);
    return __builtin_bit_cast(short, h);
}
__device__ __forceinline__ unsigned pk2(float lo, float hi) {
    return (unsigned)(unsigned short)f2b(lo) | (((unsigned)(unsigned short)f2b(hi)) << 16);
}
__device__ __forceinline__ float b2f(short s) {
    return __builtin_bit_cast(float, ((unsigned)(unsigned short)s) << 16);
}
__device__ __forceinline__ void gload_lds16(const void* g, void* lds) {
    __builtin_amdgcn_global_load_lds((const __attribute__((address_space(1))) unsigned int*)g,
                                     (__attribute__((address_space(3))) unsigned int*)lds, 16, 0, 0);
}

// ---------------- fused scatter + LayerNorm->bf16 ----------------
__global__ __launch_bounds__(256) void k_scatter_sp(const float* __restrict__ xyzp, const float* __restrict__ feat,
                                                    const float* __restrict__ ln_g, const float* __restrict__ ln_b,
                                                    int* __restrict__ grid, int* __restrict__ cxy,
                                                    short* __restrict__ sp_bf) {
    int i = blockIdx.x * 256 + threadIdx.x;
    if (i >= BB * NN) return;
    int b = i / NN;
    float4 xp = *(const float4*)(xyzp + (size_t)i * 4);
    int cx = __float2int_rn(xp.x * 256.0f);
    int cy = __float2int_rn(xp.y * 256.0f);
    cxy[i] = cx | (cy << 8);
    grid[b * GS * GS + (cy + 1) * GS + (cx + 1)] = i % NN;
    float v[CIN];
    float pn = (xp.w - 0.5f) * 2.0f;
    v[0] = fminf(fmaxf(pn, 0.0f), 1.0f);
    v[1] = -fminf(fmaxf(pn, -1.0f), 0.0f);
    const float4* f4 = (const float4*)(feat + (size_t)i * FEAT);
#pragma unroll
    for (int j = 0; j < FEAT / 4; j++) {
        float4 t = f4[j];
        v[2 + 4 * j] = t.x; v[3 + 4 * j] = t.y; v[4 + 4 * j] = t.z; v[5 + 4 * j] = t.w;
    }
    float s = 0.0f;
#pragma unroll
    for (int j = 0; j < CIN; j++) s += v[j];
    float mu = s / (float)CIN;
    float vs = 0.0f;
#pragma unroll
    for (int j = 0; j < CIN; j++) { float d = v[j] - mu; vs += d * d; }
    float inv = 1.0f / sqrtf(vs / (float)CIN + 1e-5f);
    unsigned o2[64];
#pragma unroll
    for (int j = 0; j < 33; j++) {
        float a = (v[2 * j] - mu) * inv * ln_g[2 * j] + ln_b[2 * j];
        float bqq = (2 * j + 1 < CIN) ? ((v[2 * j + 1] - mu) * inv * ln_g[2 * j + 1] + ln_b[2 * j + 1]) : 0.f;
        o2[j] = pk2(a, bqq);
    }
#pragma unroll
    for (int j = 33; j < 64; j++) o2[j] = 0;
    int4* o = (int4*)(sp_bf + (size_t)i * 128);
#pragma unroll
    for (int t = 0; t < 16; t++) o[t] = make_int4(o2[4 * t], o2[4 * t + 1], o2[4 * t + 2], o2[4 * t + 3]);
}

// ---------------- exact KNN ----------------
__device__ __forceinline__ void ins16(unsigned* a, unsigned key) {
    if (key < a[15]) {
#pragma unroll
        for (int j = 15; j >= 1; --j) {
            unsigned prev = a[j - 1];
            a[j] = (prev > key) ? prev : ((a[j] > key) ? key : a[j]);
        }
        a[0] = a[0] < key ? a[0] : key;
    }
}

__device__ __forceinline__ void cmpex(unsigned& x, unsigned& y) {
    unsigned lo = x < y ? x : y;
    unsigned hi = x < y ? y : x;
    x = lo; y = hi;
}

__device__ __forceinline__ void merge16(const unsigned* L, unsigned* c) {
#pragma unroll
    for (int i = 0; i < 16; ++i) c[i] = L[i];
#pragma unroll
    for (int s = 0; s < 4; ++s) {
        int m = 1 << s;
        unsigned bv[16];
#pragma unroll
        for (int i = 0; i < 16; ++i) bv[i] = __shfl_xor(c[15 - i], m);
#pragma unroll
        for (int i = 0; i < 16; ++i) c[i] = c[i] < bv[i] ? c[i] : bv[i];
#pragma unroll
        for (int d = 8; d >= 1; d >>= 1)
#pragma unroll
            for (int i = 0; i < 16; ++i)
                if (!(i & d)) cmpex(c[i], c[i | d]);
    }
}

__global__ __launch_bounds__(256) void k_knn(const int* __restrict__ grid, const int* __restrict__ cxy,
                                             const float* __restrict__ xyzp, float4* __restrict__ relg) {
    int tid = threadIdx.x;
    int t = tid & 15;
    int q = blockIdx.x * 16 + (tid >> 4);
    int b = q >> 12;
    int me = cxy[q];
    int mx = me & 255, my = (me >> 8) & 255;
    const int* gb = grid + b * GS * GS;
    unsigned L[16];
#pragma unroll
    for (int j = 0; j < 16; j++) L[j] = 0xFFFFFFFFu;
    for (int i = t; i < 441; i += 16) {
        int dy = i / 21 - 10, dx = i % 21 - 10;
        int Y = my + dy, X = mx + dx;
        if ((unsigned)Y >= 256u || (unsigned)X >= 256u) continue;
        int j = gb[(Y + 1) * GS + X + 1];
        if (j >= 0) ins16(L, ((unsigned)(dx * dx + dy * dy) << 12) | (unsigned)j);
    }
    unsigned c[16];
    merge16(L, c);
    for (int r = 11; r <= 256; ++r) {
        bool need = (c[15] >> 12) >= (unsigned)(r * r);
        if (!__any(need)) break;
        if (need) {
            int rr = r * r;
            for (int dx = -r + t; dx <= r; dx += 16) {
                int X = mx + dx;
                if ((unsigned)X >= 256u) continue;
                int d2t = dx * dx + rr;
                int Y0 = my - r, Y1 = my + r;
                if ((unsigned)Y0 < 256u) {
                    int j = gb[(Y0 + 1) * GS + X + 1];
                    if (j >= 0) ins16(L, ((unsigned)d2t << 12) | (unsigned)j);
                }
                if ((unsigned)Y1 < 256u) {
                    int j = gb[(Y1 + 1) * GS + X + 1];
                    if (j >= 0) ins16(L, ((unsigned)d2t << 12) | (unsigned)j);
                }
            }
            for (int dy = -r + 1 + t; dy <= r - 1; dy += 16) {
                int Y = my + dy;
                if ((unsigned)Y >= 256u) continue;
                int rowoff = (Y + 1) * GS;
                int d2s = rr + dy * dy;
                int X0 = mx - r, X1 = mx + r;
                if ((unsigned)X0 < 256u) {
                    int j = gb[rowoff + X0 + 1];
                    if (j >= 0) ins16(L, ((unsigned)d2s << 12) | (unsigned)j);
                }
                if ((unsigned)X1 < 256u) {
                    int j = gb[rowoff + X1 + 1];
                    if (j >= 0) ins16(L, ((unsigned)d2s << 12) | (unsigned)j);
                }
            }
            merge16(L, c);
        }
    }
    unsigned mine = 0;
#pragma unroll
    for (int j = 0; j < 16; ++j)
        if (t == j) mine = c[j];
    int g = (b << 12) | (int)(mine & 4095u);
    float4 mef = *(const float4*)(xyzp + (size_t)q * 4);
    float4 tt = *(const float4*)(xyzp + (size_t)g * 4);
    float4 o;
    o.x = mef.x - tt.x; o.y = mef.y - tt.y; o.z = mef.w - tt.w;
    o.w = __int_as_float(g);
    relg[(size_t)q * 16 + t] = o;
}

// ---------------- weight pre-pack (+Wf/cf fold, +at_w1 folded into W2 q/k slices, +head weights) ----------------
#define PK128_SZ (4 * 8 * 512)
#define PKW1_SZ (9 * 3 * 8 * 512)
#define PKW2_SZ (9 * 4 * 24 * 512)
#define PKH_SZ 8192
#define PACK_TOTAL (3 * PK128_SZ + PKW1_SZ + PKW2_SZ + PK128_SZ + 128 + 3 * PKH_SZ)

__global__ __launch_bounds__(256) void k_pack(const float* __restrict__ pe_w2, const float* __restrict__ at_w1,
                                              const float* __restrict__ at_w2, const float* __restrict__ W1,
                                              const float* __restrict__ W2,
                                              const float* __restrict__ pe_b2, const float* __restrict__ at_b1,
                                              const float* __restrict__ ag_w, const float* __restrict__ mlp_w1,
                                              const float* __restrict__ mlp_w2,
                                              short* __restrict__ pk_pe2, short* __restrict__ pk_a1,
                                              short* __restrict__ pk_a2, short* __restrict__ pk_w1,
                                              short* __restrict__ pk_w2, short* __restrict__ pk_wf,
                                              float* __restrict__ cf, short* __restrict__ pk_ag,
                                              short* __restrict__ pk_m1, short* __restrict__ pk_m2) {
    int i = blockIdx.x * 256 + threadIdx.x;
    if (i < 3 * PK128_SZ) {
        int seg = i / PK128_SZ, r = i % PK128_SZ;
        int f = r / 512, q = r % 512;
        int lane = q / 8, j = q % 8;
        int kt = f / 8, nt = f % 8;
        int k = kt * 32 + (lane >> 4) * 8 + j, n = nt * 16 + (lane & 15);
        const float* W = (seg == 0) ? pe_w2 : (seg == 1) ? at_w1 : at_w2;
        short* dst = (seg == 0) ? pk_pe2 : (seg == 1) ? pk_a1 : pk_a2;
        dst[r] = f2b(W[k * 128 + n]);
        return;
    }
    i -= 3 * PK128_SZ;
    if (i < PKW1_SZ) {
        int f = i / 512, q = i % 512;
        int lane = q / 8, j = q % 8;
        int tap = f / 24, rem = f % 24;
        int kt = rem / 8, nt = rem % 8;
        int k = kt * 32 + (lane >> 4) * 8 + j, n = nt * 16 + (lane & 15);
        pk_w1[i] = (k < CIN) ? f2b(W1[(tap * CIN + k) * 128 + n]) : (short)0;
        return;
    }
    i -= PKW1_SZ;
    if (i < PKW2_SZ) {
        int f = i / 512, q = i % 512;
        int lane = q / 8, j = q % 8;
        int tap = f / 96, rem = f % 96;
        int kt = rem / 24, nt = rem % 24;
        int k = kt * 32 + (lane >> 4) * 8 + j, n = nt * 16 + (lane & 15);
        float acc;
        if (n < 256) {
            int sel = n >> 7, cc = n & 127;
            acc = 0.f;
            for (int m = 0; m < 128; ++m)
                acc += W2[((size_t)(tap * 128 + k)) * 384 + 3 * m + sel] * at_w1[m * 128 + cc];
        } else {
            acc = W2[((size_t)(tap * 128 + k)) * 384 + 3 * (n - 256) + 2];
        }
        pk_w2[i] = f2b(acc);
        return;
    }
    i -= PKW2_SZ;
    if (i < PK128_SZ) {
        int ii = i >> 7, j = i & 127;
        float acc = 0.f;
        for (int m = 0; m < 128; ++m) acc += pe_w2[ii * 128 + m] * at_w1[m * 128 + j];
        int lane = (((ii >> 3) & 3) << 4) | (j & 15);
        int dst = ((ii >> 5) * 8 + (j >> 4)) * 512 + lane * 8 + (ii & 7);
        pk_wf[dst] = f2b(acc);
        return;
    }
    i -= PK128_SZ;
    if (i < 128) {
        float acc = at_b1[i];
        for (int m = 0; m < 128; ++m) acc += pe_b2[m] * at_w1[m * 128 + i];
        cf[i] = acc;
        return;
    }
    i -= 128;
    if (i < PKH_SZ) {
        int f = i / 512, q = i % 512;
        int lane = q / 8, j = q % 8;
        int kt = f >> 2, nt = f & 3;
        int k = kt * 32 + (lane >> 4) * 8 + j, n = nt * 16 + (lane & 15);
        pk_ag[i] = f2b(ag_w[k * 64 + n]);
        return;
    }
    i -= PKH_SZ;
    if (i < PKH_SZ) {
        int f = i / 512, q = i % 512;
        int lane = q / 8, j = q % 8;
        int kt = f >> 3, nt = f & 7;
        int k = kt * 32 + (lane >> 4) * 8 + j, n = nt * 16 + (lane & 15);
        pk_m1[i] = f2b(mlp_w1[k * 128 + n]);
        return;
    }
    i -= PKH_SZ;
    if (i < PKH_SZ) {
        int f = i / 512, q = i % 512;
        int lane = q / 8, j = q % 8;
        int kt = f >> 2, nt = f & 3;
        int k = kt * 32 + (lane >> 4) * 8 + j, n = nt * 16 + (lane & 15);
        pk_m2[i] = f2b(mlp_w2[k * 64 + n]);
    }
}

// ---------------- conv1 (MFMA, 64-row blocks, DMA double-buffered) ----------------
__global__ __launch_bounds__(256, 4) void k_conv1(const int* __restrict__ grid, const int* __restrict__ cxy,
                                                  const short* __restrict__ sp_bf, const float* __restrict__ b1,
                                                  const short* __restrict__ pk_w1, const short* __restrict__ zero256,
                                                  short* __restrict__ h1_bf) {
    __shared__ int sj[9][64];
    __shared__ __align__(16) char sb[2][64 * 256];
    int row0 = blockIdx.x * 64;
    int b = row0 / NN;
    int tid = threadIdx.x;
    int w = tid >> 6, l = tid & 63, cl = l & 15;
    for (int e = tid; e < 9 * 64; e += 256) {
        int k = e / 64, p = e % 64;
        int me = cxy[row0 + p];
        sj[k][p] = grid[b * GS * GS + (((me >> 8) & 255) + k / 3) * GS + ((me & 255) + k % 3)];
    }
    __syncthreads();
    f32x4 acc[4][2];
#pragma unroll
    for (int m = 0; m < 4; m++)
#pragma unroll
        for (int nt = 0; nt < 2; nt++) acc[m][nt] = (f32x4){0.f, 0.f, 0.f, 0.f};

#define STAGE1(bufp, tap)                                                                      \
    {                                                                                          \
        _Pragma("unroll") for (int i = 0; i < 4; ++i) {                                        \
            int row = w * 16 + i * 4 + (l >> 4);                                               \
            int j = sj[tap][row];                                                              \
            int srcch = cl ^ (row & 7);                                                        \
            const short* src = (j >= 0) ? (sp_bf + ((size_t)(b * NN + j) * 128 + srcch * 8))   \
                                        : (zero256 + srcch * 8);                               \
            gload_lds16(src, (bufp) + (w * 16 + i * 4) * 256);                                 \
        }                                                                                      \
    }
    STAGE1(&sb[0][0], 0);
    asm volatile("s_waitcnt vmcnt(0)" ::: "memory");
    __syncthreads();
    int cur = 0;
    for (int tap = 0; tap < 9; ++tap) {
        if (tap < 8) STAGE1(&sb[cur ^ 1][0], tap + 1);
        const char* base = &sb[cur][0];
#pragma unroll
        for (int kt = 0; kt < 3; ++kt) {
            bf16x8 a[4];
#pragma unroll
            for (int m = 0; m < 4; ++m) {
                int row = m * 16 + (l & 15);
                a[m] = *(const bf16x8*)&base[row * 256 + ((kt * 64 + (l >> 4) * 16) ^ ((row & 7) << 4))];
            }
#pragma unroll
            for (int nt = 0; nt < 2; ++nt) {
                bf16x8 bv = *(const bf16x8*)(pk_w1 + (size_t)(((tap * 3 + kt) * 8 + w * 2 + nt) * 64 + l) * 8);
#pragma unroll
                for (int m = 0; m < 4; ++m) acc[m][nt] = MFMA_B16(a[m], bv, acc[m][nt]);
            }
        }
        asm volatile("s_waitcnt vmcnt(0)" ::: "memory");
        __syncthreads();
        cur ^= 1;
    }
#pragma unroll
    for (int nt = 0; nt < 2; ++nt) {
        int col = (w * 2 + nt) * 16 + cl;
        float bb = b1[col];
#pragma unroll
        for (int m = 0; m < 4; ++m)
#pragma unroll
            for (int j = 0; j < 4; ++j) {
                int row = row0 + m * 16 + (l >> 4) * 4 + j;
                h1_bf[(size_t)row * 128 + col] = f2b(acc[m][nt][j] + bb);
            }
    }
}

// ---------------- conv2 (folded): emits q1 (+cf), k1, v directly ----------------
__global__ __launch_bounds__(256, 4) void k_conv2(const int* __restrict__ grid, const int* __restrict__ cxy,
                                                  const short* __restrict__ h1_bf, const short* __restrict__ pk_w2,
                                                  const short* __restrict__ zero256, const float* __restrict__ cf,
                                                  short* __restrict__ q1, short* __restrict__ k1,
                                                  short* __restrict__ vg) {
    __shared__ int sj[9][64];
    __shared__ __align__(16) char sb[2][64 * 256];
    int bid = blockIdx.x;
    int nb = bid % 3, mb = bid / 3;
    int row0 = mb * 64;
    int b = row0 / NN;
    int tid = threadIdx.x;
    int w = tid >> 6, l = tid & 63, cl = l & 15;
    for (int e = tid; e < 9 * 64; e += 256) {
        int k = e / 64, p = e % 64;
        int me = cxy[row0 + p];
        sj[k][p] = grid[b * GS * GS + (((me >> 8) & 255) + k / 3) * GS + ((me & 255) + k % 3)];
    }
    __syncthreads();
    f32x4 acc[4][2];
#pragma unroll
    for (int m = 0; m < 4; m++)
#pragma unroll
        for (int nt = 0; nt < 2; nt++) acc[m][nt] = (f32x4){0.f, 0.f, 0.f, 0.f};

#define STAGE2(bufp, tap)                                                                      \
    {                                                                                          \
        _Pragma("unroll") for (int i = 0; i < 4; ++i) {                                        \
            int row = w * 16 + i * 4 + (l >> 4);                                               \
            int j = sj[tap][row];                                                              \
            int srcch = cl ^ (row & 7);                                                        \
            const short* src = (j >= 0) ? (h1_bf + ((size_t)(b * NN + j) * 128 + srcch * 8))   \
                                        : (zero256 + srcch * 8);                               \
            gload_lds16(src, (bufp) + (w * 16 + i * 4) * 256);                                 \
        }                                                                                      \
    }
    STAGE2(&sb[0][0], 0);
    asm volatile("s_waitcnt vmcnt(0)" ::: "memory");
    __syncthreads();
    int cur = 0;
    for (int tap = 0; tap < 9; ++tap) {
        if (tap < 8) STAGE2(&sb[cur ^ 1][0], tap + 1);
        const char* base = &sb[cur][0];
#pragma unroll
        for (int kt = 0; kt < 4; ++kt) {
            bf16x8 a[4];
#pragma unroll
            for (int m = 0; m < 4; ++m) {
                int row = m * 16 + (l & 15);
                a[m] = *(const bf16x8*)&base[row * 256 + ((kt * 64 + (l >> 4) * 16) ^ ((row & 7) << 4))];
            }
#pragma unroll
            for (int nt = 0; nt < 2; ++nt) {
                bf16x8 bv = *(const bf16x8*)(pk_w2 + (size_t)(((tap * 4 + kt) * 24 + nb * 8 + w * 2 + nt) * 64 + l) * 8);
#pragma unroll
                for (int m = 0; m < 4; ++m) acc[m][nt] = MFMA_B16(a[m], bv, acc[m][nt]);
            }
        }
        asm volatile("s_waitcnt vmcnt(0)" ::: "memory");
        __syncthreads();
        cur ^= 1;
    }
#pragma unroll
    for (int nt = 0; nt < 2; ++nt) {
        int col = nb * 128 + (w * 2 + nt) * 16 + cl;
        int seg = col >> 7, dd = col & 127;
        short* dst = (seg == 0) ? q1 : (seg == 1) ? k1 : vg;
        float cadd = (seg == 0) ? cf[dd] : 0.f;
#pragma unroll
        for (int m = 0; m < 4; ++m)
#pragma unroll
            for (int j = 0; j < 4; ++j) {
                int row = row0 + m * 16 + (l >> 4) * 4 + j;
                dst[(size_t)row * 128 + dd] = f2b(acc[m][nt][j] + cadd);
            }
    }
}

// ---------------- fused attention (occupancy-freed: launch_bounds(256,5)) ----------------
__global__ __launch_bounds__(256, 5) void k_attn(const float4* __restrict__ relg,
                                                 const short* __restrict__ q1g, const short* __restrict__ k1g,
                                                 const short* __restrict__ vg,
                                                 const float* __restrict__ pe_w1, const float* __restrict__ pe_b1,
                                                 const float* __restrict__ pe_b2, const float* __restrict__ at_b2,
                                                 const short* __restrict__ pk_pe2, const short* __restrict__ pk_wf,
                                                 const short* __restrict__ pk_a2, short* __restrict__ res1b) {
    __shared__ __align__(16) char WK[64 * 256];
    __shared__ float4 s_rel[64];
    __shared__ int s_g[64];
    int tid = threadIdx.x;
    int w = tid >> 6, l = tid & 63, cl = l & 15;
    int P0 = blockIdx.x * 4;

    if (l < 16) {
        float4 f4 = relg[(size_t)(P0 + w) * 16 + l];
        s_rel[w * 16 + l] = f4;
        s_g[w * 16 + l] = __float_as_int(f4.w);
    }
    {
        int c0 = 2 * l;
        float wa0 = pe_w1[c0], wa1 = pe_w1[c0 + 1];
        float wb0 = pe_w1[128 + c0], wb1 = pe_w1[129 + c0];
        float wc0 = pe_w1[256 + c0], wc1 = pe_w1[257 + c0];
        float ba0 = pe_b1[c0], ba1 = pe_b1[c0 + 1];
#pragma unroll
        for (int lr = 0; lr < 16; ++lr) {
            float4 rel = s_rel[w * 16 + lr];
            float h0 = fmaxf(rel.x * wa0 + rel.y * wb0 + rel.z * wc0 + ba0, 0.f);
            float h1v = fmaxf(rel.x * wa1 + rel.y * wb1 + rel.z * wc1 + ba1, 0.f);
            *(unsigned*)&WK[(w * 16 + lr) * 256 + ((4 * l) ^ SWZ(lr))] = pk2(h0, h1v);
        }
    }
    __syncthreads();  // B1
    unsigned k1p[4][4];
    unsigned q1p[4];
#pragma unroll
    for (int m = 0; m < 4; ++m) {
#pragma unroll
        for (int j = 0; j < 4; ++j) {
            int g = s_g[m * 16 + (l >> 4) * 4 + j];
            unsigned lo = *((const unsigned short*)k1g + (size_t)g * 128 + w * 32 + cl);
            unsigned hi = *((const unsigned short*)k1g + (size_t)g * 128 + w * 32 + 16 + cl);
            k1p[m][j] = lo | (hi << 16);
        }
        unsigned qlo = *((const unsigned short*)q1g + (size_t)(P0 + m) * 128 + w * 32 + cl);
        unsigned qhi = *((const unsigned short*)q1g + (size_t)(P0 + m) * 128 + w * 32 + 16 + cl);
        q1p[m] = qlo | (qhi << 16);
    }
    unsigned pe_pk[4][2][2];
    {
        f32x4 pacc[4][2];
#pragma unroll
        for (int m = 0; m < 4; m++)
#pragma unroll
            for (int nt = 0; nt < 2; nt++) pacc[m][nt] = (f32x4){0.f, 0.f, 0.f, 0.f};
#pragma unroll
        for (int kt = 0; kt < 4; ++kt) {
            int off = kt * 64 + (l >> 4) * 16;
            bf16x8 a[4];
#pragma unroll
            for (int m = 0; m < 4; ++m) {
                int ra = m * 16 + (l & 15);
                a[m] = *(const bf16x8*)&WK[ra * 256 + (off ^ SWZ(ra))];
            }
#pragma unroll
            for (int nt = 0; nt < 2; ++nt) {
                bf16x8 bv = *(const bf16x8*)(pk_pe2 + (size_t)((kt * 8 + w * 2 + nt) * 64 + l) * 8);
#pragma unroll
                for (int m = 0; m < 4; ++m) pacc[m][nt] = MFMA_B16(a[m], bv, pacc[m][nt]);
            }
        }
#pragma unroll
        for (int nt = 0; nt < 2; ++nt) {
            float b2v = pe_b2[w * 32 + nt * 16 + cl];
#pragma unroll
            for (int m = 0; m < 4; ++m) {
                pe_pk[m][nt][0] = pk2(pacc[m][nt][0] + b2v, pacc[m][nt][1] + b2v);
                pe_pk[m][nt][1] = pk2(pacc[m][nt][2] + b2v, pacc[m][nt][3] + b2v);
            }
        }
    }
    f32x4 facc[4][2];
#pragma unroll
    for (int m = 0; m < 4; m++)
#pragma unroll
        for (int nt = 0; nt < 2; nt++) facc[m][nt] = (f32x4){0.f, 0.f, 0.f, 0.f};
#pragma unroll
    for (int kt = 0; kt < 4; ++kt) {
        int off = kt * 64 + (l >> 4) * 16;
        bf16x8 a[4];
#pragma unroll
        for (int m = 0; m < 4; ++m) {
            int ra = m * 16 + (l & 15);
            a[m] = *(const bf16x8*)&WK[ra * 256 + (off ^ SWZ(ra))];
        }
#pragma unroll
        for (int nt = 0; nt < 2; ++nt) {
            bf16x8 bv = *(const bf16x8*)(pk_wf + (size_t)((kt * 8 + w * 2 + nt) * 64 + l) * 8);
#pragma unroll
            for (int m = 0; m < 4; ++m) facc[m][nt] = MFMA_B16(a[m], bv, facc[m][nt]);
        }
    }
    __syncthreads();  // B2
#pragma unroll
    for (int m = 0; m < 4; ++m)
#pragma unroll
        for (int nt = 0; nt < 2; ++nt) {
            int col = w * 32 + nt * 16 + cl;
            float qv = b2f((short)((q1p[m] >> (nt * 16)) & 0xffff));
#pragma unroll
            for (int j = 0; j < 4; ++j) {
                int rr = m * 16 + (l >> 4) * 4 + j;
                float kv = b2f((short)((k1p[m][j] >> (nt * 16)) & 0xffff));
                float x = facc[m][nt][j] + qv - kv;
                *(short*)&WK[rr * 256 + ((col * 2) ^ SWZ(rr))] = f2b(fmaxf(x, 0.f));
            }
        }
    unsigned vp[4][4];
#pragma unroll
    for (int m = 0; m < 4; ++m)
#pragma unroll
        for (int j = 0; j < 4; ++j) {
            int g = s_g[m * 16 + (l >> 4) * 4 + j];
            unsigned lo = *((const unsigned short*)vg + (size_t)g * 128 + w * 32 + cl);
            unsigned hi = *((const unsigned short*)vg + (size_t)g * 128 + w * 32 + 16 + cl);
            vp[m][j] = lo | (hi << 16);
        }
    __syncthreads();  // B3
#pragma unroll
    for (int m = 0; m < 4; m++)
#pragma unroll
        for (int nt = 0; nt < 2; nt++) facc[m][nt] = (f32x4){0.f, 0.f, 0.f, 0.f};
#pragma unroll
    for (int kt = 0; kt < 4; ++kt) {
        int off = kt * 64 + (l >> 4) * 16;
        bf16x8 a[4];
#pragma unroll
        for (int m = 0; m < 4; ++m) {
            int ra = m * 16 + (l & 15);
            a[m] = *(const bf16x8*)&WK[ra * 256 + (off ^ SWZ(ra))];
        }
#pragma unroll
        for (int nt = 0; nt < 2; ++nt) {
            bf16x8 bv = *(const bf16x8*)(pk_a2 + (size_t)((kt * 8 + w * 2 + nt) * 64 + l) * 8);
#pragma unroll
            for (int m = 0; m < 4; ++m) facc[m][nt] = MFMA_B16(a[m], bv, facc[m][nt]);
        }
    }
    // max-free softmax in base 2 (softmax shift-invariance; scores bounded)
    const float scale2 = 0.08838834764831845f * 1.4426950408889634f;
#pragma unroll
    for (int m = 0; m < 4; ++m)
#pragma unroll
        for (int nt = 0; nt < 2; ++nt) {
            int col = w * 32 + nt * 16 + cl;
            float bv = at_b2[col];
            float ee[4], es = 0.f;
#pragma unroll
            for (int j = 0; j < 4; ++j) {
                ee[j] = exp2f((facc[m][nt][j] + bv) * scale2);
                es += ee[j];
            }
            es += __shfl_xor(es, 16);
            es += __shfl_xor(es, 32);
            float pev[4];
            pev[0] = b2f((short)(pe_pk[m][nt][0] & 0xffff));
            pev[1] = b2f((short)(pe_pk[m][nt][0] >> 16));
            pev[2] = b2f((short)(pe_pk[m][nt][1] & 0xffff));
            pev[3] = b2f((short)(pe_pk[m][nt][1] >> 16));
            float o = 0.f;
#pragma unroll
            for (int j = 0; j < 4; ++j) {
                float vvv = b2f((short)((vp[m][j] >> (nt * 16)) & 0xffff));
                o += ee[j] * (vvv + pev[j]);
            }
            o += __shfl_xor(o, 16);
            o += __shfl_xor(o, 32);
            if (l < 16) res1b[(size_t)(P0 + m) * 128 + col] = f2b(o / es);
        }
}

// ---------------- head (MFMA) ----------------
__global__ __launch_bounds__(256) void k_head(const short* __restrict__ res1b, const float* __restrict__ feat,
                                              const float* __restrict__ ag_b, const float* __restrict__ mlp_b1,
                                              const float* __restrict__ mlp_b2,
                                              const short* __restrict__ pk_ag, const short* __restrict__ pk_m1,
                                              const short* __restrict__ pk_m2, float* __restrict__ out) {
    __shared__ __align__(16) char sA[64 * 256];
    __shared__ __align__(16) char r1s[64 * 128];
    int tid = threadIdx.x;
    int w = tid >> 6, l = tid & 63, cl = l & 15;
    int i0 = blockIdx.x * 64;
    for (int e = tid; e < 1024; e += 256) {
        int row = e >> 4, sl = e & 15;
        gload_lds16(res1b + ((size_t)(i0 + row) * 128 + (sl ^ (row & 7)) * 8), &sA[e * 16]);
    }
    asm volatile("s_waitcnt vmcnt(0)" ::: "memory");
    __syncthreads();
    {
        f32x4 acc[4];
#pragma unroll
        for (int m = 0; m < 4; m++) acc[m] = (f32x4){0.f, 0.f, 0.f, 0.f};
#pragma unroll
        for (int kt = 0; kt < 4; ++kt) {
            bf16x8 a[4];
#pragma unroll
            for (int m = 0; m < 4; ++m) {
                int row = m * 16 + (l & 15);
                a[m] = *(const bf16x8*)&sA[row * 256 + ((kt * 64 + (l >> 4) * 16) ^ ((row & 7) << 4))];
            }
            bf16x8 bv = *(const bf16x8*)(pk_ag + (size_t)((kt * 4 + w) * 64 + l) * 8);
#pragma unroll
            for (int m = 0; m < 4; ++m) acc[m] = MFMA_B16(a[m], bv, acc[m]);
        }
        int col = w * 16 + cl;
        float bb = ag_b[col];
#pragma unroll
        for (int m = 0; m < 4; ++m)
#pragma unroll
            for (int j = 0; j < 4; ++j) {
                int row = m * 16 + (l >> 4) * 4 + j;
                float val = acc[m][j] + bb + feat[(size_t)(i0 + row) * 64 + col];
                *(short*)&r1s[row * 128 + ((col * 2) ^ ((row & 7) << 4))] = f2b(val);
            }
    }
    __syncthreads();
    {
        f32x4 acc[4][2];
#pragma unroll
        for (int m = 0; m < 4; m++)
#pragma unroll
            for (int nt = 0; nt < 2; nt++) acc[m][nt] = (f32x4){0.f, 0.f, 0.f, 0.f};
#pragma unroll
        for (int kt = 0; kt < 2; ++kt) {
            bf16x8 a[4];
#pragma unroll
            for (int m = 0; m < 4; ++m) {
                int row = m * 16 + (l & 15);
                a[m] = *(const bf16x8*)&r1s[row * 128 + ((kt * 64 + (l >> 4) * 16) ^ ((row & 7) << 4))];
            }
#pragma unroll
            for (int nt = 0; nt < 2; ++nt) {
                bf16x8 bv = *(const bf16x8*)(pk_m1 + (size_t)((kt * 8 + w * 2 + nt) * 64 + l) * 8);
#pragma unroll
                for (int m = 0; m < 4; ++m) acc[m][nt] = MFMA_B16(a[m], bv, acc[m][nt]);
            }
        }
#pragma unroll
        for (int nt = 0; nt < 2; ++nt) {
            int col = (w * 2 + nt) * 16 + cl;
            float bb = mlp_b1[col];
#pragma unroll
            for (int m = 0; m < 4; ++m)
#pragma unroll
                for (int j = 0; j < 4; ++j) {
                    int row = m * 16 + (l >> 4) * 4 + j;
                    float x = acc[m][nt][j] + bb;
                    float g = 0.5f * x * (1.0f + erff(x * 0.70710678118654752f));
                    *(short*)&sA[row * 256 + ((col * 2) ^ ((row & 7) << 4))] = f2b(g);
                }
        }
    }
    __syncthreads();
    {
        f32x4 acc[4];
#pragma unroll
        for (int m = 0; m < 4; m++) acc[m] = (f32x4){0.f, 0.f, 0.f, 0.f};
#pragma unroll
        for (int kt = 0; kt < 4; ++kt) {
            bf16x8 a[4];
#pragma unroll
            for (int m = 0; m < 4; ++m) {
                int row = m * 16 + (l & 15);
                a[m] = *(const bf16x8*)&sA[row * 256 + ((kt * 64 + (l >> 4) * 16) ^ ((row & 7) << 4))];
            }
            bf16x8 bv = *(const bf16x8*)(pk_m2 + (size_t)((kt * 4 + w) * 64 + l) * 8);
#pragma unroll
            for (int m = 0; m < 4; ++m) acc[m] = MFMA_B16(a[m], bv, acc[m]);
        }
        int col = w * 16 + cl;
        float bb = mlp_b2[col];
#pragma unroll
        for (int m = 0; m < 4; ++m)
#pragma unroll
            for (int j = 0; j < 4; ++j) {
                int row = m * 16 + (l >> 4) * 4 + j;
                out[(size_t)(i0 + row) * 64 + col] = acc[m][j] + bb + feat[(size_t)(i0 + row) * 64 + col];
            }
    }
}

extern "C" void kernel_launch(void* const* d_in, const int* in_sizes, int n_in,
                              void* d_out, int out_size, void* d_ws, size_t ws_size,
                              hipStream_t stream) {
    const float* xyzp = (const float*)d_in[0];
    const float* features = (const float*)d_in[1];
    const float* ln_g = (const float*)d_in[2];
    const float* ln_b = (const float*)d_in[3];
    const float* W1 = (const float*)d_in[4];
    const float* b1 = (const float*)d_in[5];
    const float* W2 = (const float*)d_in[6];
    const float* pe_w1 = (const float*)d_in[7];
    const float* pe_b1 = (const float*)d_in[8];
    const float* pe_w2 = (const float*)d_in[9];
    const float* pe_b2 = (const float*)d_in[10];
    const float* at_w1 = (const float*)d_in[11];
    const float* at_b1 = (const float*)d_in[12];
    const float* at_w2 = (const float*)d_in[13];
    const float* at_b2 = (const float*)d_in[14];
    const float* ag_w = (const float*)d_in[15];
    const float* ag_b = (const float*)d_in[16];
    const float* mlp_w1 = (const float*)d_in[17];
    const float* mlp_b1 = (const float*)d_in[18];
    const float* mlp_w2 = (const float*)d_in[19];
    const float* mlp_b2 = (const float*)d_in[20];
    float* out = (float*)d_out;

    char* w = (char*)d_ws;
    auto alloc = [&](size_t bytes) { char* pp = w; w += (bytes + 255) & ~(size_t)255; return pp; };
    int* grid = (int*)alloc((size_t)BB * GS * GS * 4);
    short* zero256 = (short*)alloc(256);
    int* cxy = (int*)alloc((size_t)BB * NN * 4);
    float4* relg = (float4*)alloc((size_t)BB * NN * KNN * 16);
    short* sp_bf = (short*)alloc((size_t)BB * NN * 128 * 2);
    short* h1_bf = (short*)alloc((size_t)BB * NN * HID * 2);
    short* q1 = (short*)alloc((size_t)BB * NN * HID * 2);
    short* k1 = (short*)alloc((size_t)BB * NN * HID * 2);
    short* vg = (short*)alloc((size_t)BB * NN * HID * 2);
    short* res1b = (short*)alloc((size_t)BB * NN * HID * 2);
    short* pk_pe2 = (short*)alloc((size_t)PK128_SZ * 2);
    short* pk_a1 = (short*)alloc((size_t)PK128_SZ * 2);
    short* pk_a2 = (short*)alloc((size_t)PK128_SZ * 2);
    short* pk_wf = (short*)alloc((size_t)PK128_SZ * 2);
    short* pk_w1 = (short*)alloc((size_t)PKW1_SZ * 2);
    short* pk_w2 = (short*)alloc((size_t)PKW2_SZ * 2);
    short* pk_ag = (short*)alloc((size_t)PKH_SZ * 2);
    short* pk_m1 = (short*)alloc((size_t)PKH_SZ * 2);
    short* pk_m2 = (short*)alloc((size_t)PKH_SZ * 2);
    float* cf = (float*)alloc(128 * 4);

    hipMemsetAsync(grid, 0xFF, (size_t)BB * GS * GS * 4, stream);
    hipMemsetAsync(zero256, 0, 256, stream);
    k_scatter_sp<<<(BB * NN + 255) / 256, 256, 0, stream>>>(xyzp, features, ln_g, ln_b, grid, cxy, sp_bf);
    k_pack<<<(PACK_TOTAL + 255) / 256, 256, 0, stream>>>(
        pe_w2, at_w1, at_w2, W1, W2, pe_b2, at_b1, ag_w, mlp_w1, mlp_w2,
        pk_pe2, pk_a1, pk_a2, pk_w1, pk_w2, pk_wf, cf, pk_ag, pk_m1, pk_m2);
    k_knn<<<BB * NN / 16, 256, 0, stream>>>(grid, cxy, xyzp, relg);
    k_conv1<<<BB * NN / 64, 256, 0, stream>>>(grid, cxy, sp_bf, b1, pk_w1, zero256, h1_bf);
    k_conv2<<<(BB * NN / 64) * 3, 256, 0, stream>>>(grid, cxy, h1_bf, pk_w2, zero256, cf, q1, k1, vg);
    k_attn<<<BB * NN / 4, 256, 0, stream>>>(relg, q1, k1, vg, pe_w1, pe_b1, pe_b2, at_b2,
                                            pk_pe2, pk_wf, pk_a2, res1b);
    k_head<<<BB * NN / 64, 256, 0, stream>>>(res1b, features, ag_b, mlp_b1, mlp_b2, pk_ag, pk_m1, pk_m2, out);
}

// Round 18
// 221.568 us; speedup vs baseline: 1.3240x; 1.3240x over previous
//
#include <hip/hip_runtime.h>
#include <hip/hip_bf16.h>
#include <math.h>

#define BB 4
#define NN 4096
#define FEAT 64
#define HID 128
#define KNN 16
#define GS 258
#define CIN 66

typedef __attribute__((ext_vector_type(8))) short bf16x8;
typedef __attribute__((ext_vector_type(4))) float f32x4;
#define MFMA_B16(a, b, c) __builtin_amdgcn_mfma_f32_16x16x32_bf16(a, b, c, 0, 0, 0)
#define SWZ(r) ((((r) & 7) << 4) ^ (((r) & 8) << 2))

__device__ __forceinline__ short f2b(float f) {
    __hip_bfloat16 h = __float2bfloat16(f);
    return __builtin_bit_cast(short, h);
}
__device__ __forceinline__ unsigned pk2(float lo, float hi) {
    return (unsigned)(unsigned short)f2b(lo) | (((unsigned)(unsigned short)f2b(hi)) << 16);
}
__device__ __forceinline__ float b2f(short s) {
    return __builtin_bit_cast(float, ((unsigned)(unsigned short)s) << 16);
}
__device__ __forceinline__ void gload_lds16(const void* g, void* lds) {
    __builtin_amdgcn_global_load_lds((const __attribute__((address_space(1))) unsigned int*)g,
                                     (__attribute__((address_space(3))) unsigned int*)lds, 16, 0, 0);
}

// ---------------- fused scatter + LayerNorm->bf16 ----------------
__global__ __launch_bounds__(256) void k_scatter_sp(const float* __restrict__ xyzp, const float* __restrict__ feat,
                                                    const float* __restrict__ ln_g, const float* __restrict__ ln_b,
                                                    int* __restrict__ grid, int* __restrict__ cxy,
                                                    short* __restrict__ sp_bf) {
    int i = blockIdx.x * 256 + threadIdx.x;
    if (i >= BB * NN) return;
    int b = i / NN;
    float4 xp = *(const float4*)(xyzp + (size_t)i * 4);
    int cx = __float2int_rn(xp.x * 256.0f);
    int cy = __float2int_rn(xp.y * 256.0f);
    cxy[i] = cx | (cy << 8);
    grid[b * GS * GS + (cy + 1) * GS + (cx + 1)] = i % NN;
    float v[CIN];
    float pn = (xp.w - 0.5f) * 2.0f;
    v[0] = fminf(fmaxf(pn, 0.0f), 1.0f);
    v[1] = -fminf(fmaxf(pn, -1.0f), 0.0f);
    const float4* f4 = (const float4*)(feat + (size_t)i * FEAT);
#pragma unroll
    for (int j = 0; j < FEAT / 4; j++) {
        float4 t = f4[j];
        v[2 + 4 * j] = t.x; v[3 + 4 * j] = t.y; v[4 + 4 * j] = t.z; v[5 + 4 * j] = t.w;
    }
    float s = 0.0f;
#pragma unroll
    for (int j = 0; j < CIN; j++) s += v[j];
    float mu = s / (float)CIN;
    float vs = 0.0f;
#pragma unroll
    for (int j = 0; j < CIN; j++) { float d = v[j] - mu; vs += d * d; }
    float inv = 1.0f / sqrtf(vs / (float)CIN + 1e-5f);
    unsigned o2[64];
#pragma unroll
    for (int j = 0; j < 33; j++) {
        float a = (v[2 * j] - mu) * inv * ln_g[2 * j] + ln_b[2 * j];
        float bqq = (2 * j + 1 < CIN) ? ((v[2 * j + 1] - mu) * inv * ln_g[2 * j + 1] + ln_b[2 * j + 1]) : 0.f;
        o2[j] = pk2(a, bqq);
    }
#pragma unroll
    for (int j = 33; j < 64; j++) o2[j] = 0;
    int4* o = (int4*)(sp_bf + (size_t)i * 128);
#pragma unroll
    for (int t = 0; t < 16; t++) o[t] = make_int4(o2[4 * t], o2[4 * t + 1], o2[4 * t + 2], o2[4 * t + 3]);
}

// ---------------- exact KNN ----------------
__device__ __forceinline__ void ins16(unsigned* a, unsigned key) {
    if (key < a[15]) {
#pragma unroll
        for (int j = 15; j >= 1; --j) {
            unsigned prev = a[j - 1];
            a[j] = (prev > key) ? prev : ((a[j] > key) ? key : a[j]);
        }
        a[0] = a[0] < key ? a[0] : key;
    }
}

__device__ __forceinline__ void cmpex(unsigned& x, unsigned& y) {
    unsigned lo = x < y ? x : y;
    unsigned hi = x < y ? y : x;
    x = lo; y = hi;
}

__device__ __forceinline__ void merge16(const unsigned* L, unsigned* c) {
#pragma unroll
    for (int i = 0; i < 16; ++i) c[i] = L[i];
#pragma unroll
    for (int s = 0; s < 4; ++s) {
        int m = 1 << s;
        unsigned bv[16];
#pragma unroll
        for (int i = 0; i < 16; ++i) bv[i] = __shfl_xor(c[15 - i], m);
#pragma unroll
        for (int i = 0; i < 16; ++i) c[i] = c[i] < bv[i] ? c[i] : bv[i];
#pragma unroll
        for (int d = 8; d >= 1; d >>= 1)
#pragma unroll
            for (int i = 0; i < 16; ++i)
                if (!(i & d)) cmpex(c[i], c[i | d]);
    }
}

__global__ __launch_bounds__(256) void k_knn(const int* __restrict__ grid, const int* __restrict__ cxy,
                                             const float* __restrict__ xyzp, float4* __restrict__ relg) {
    int tid = threadIdx.x;
    int t = tid & 15;
    int q = blockIdx.x * 16 + (tid >> 4);
    int b = q >> 12;
    int me = cxy[q];
    int mx = me & 255, my = (me >> 8) & 255;
    const int* gb = grid + b * GS * GS;
    unsigned L[16];
#pragma unroll
    for (int j = 0; j < 16; j++) L[j] = 0xFFFFFFFFu;
    for (int i = t; i < 441; i += 16) {
        int dy = i / 21 - 10, dx = i % 21 - 10;
        int Y = my + dy, X = mx + dx;
        if ((unsigned)Y >= 256u || (unsigned)X >= 256u) continue;
        int j = gb[(Y + 1) * GS + X + 1];
        if (j >= 0) ins16(L, ((unsigned)(dx * dx + dy * dy) << 12) | (unsigned)j);
    }
    unsigned c[16];
    merge16(L, c);
    for (int r = 11; r <= 256; ++r) {
        bool need = (c[15] >> 12) >= (unsigned)(r * r);
        if (!__any(need)) break;
        if (need) {
            int rr = r * r;
            for (int dx = -r + t; dx <= r; dx += 16) {
                int X = mx + dx;
                if ((unsigned)X >= 256u) continue;
                int d2t = dx * dx + rr;
                int Y0 = my - r, Y1 = my + r;
                if ((unsigned)Y0 < 256u) {
                    int j = gb[(Y0 + 1) * GS + X + 1];
                    if (j >= 0) ins16(L, ((unsigned)d2t << 12) | (unsigned)j);
                }
                if ((unsigned)Y1 < 256u) {
                    int j = gb[(Y1 + 1) * GS + X + 1];
                    if (j >= 0) ins16(L, ((unsigned)d2t << 12) | (unsigned)j);
                }
            }
            for (int dy = -r + 1 + t; dy <= r - 1; dy += 16) {
                int Y = my + dy;
                if ((unsigned)Y >= 256u) continue;
                int rowoff = (Y + 1) * GS;
                int d2s = rr + dy * dy;
                int X0 = mx - r, X1 = mx + r;
                if ((unsigned)X0 < 256u) {
                    int j = gb[rowoff + X0 + 1];
                    if (j >= 0) ins16(L, ((unsigned)d2s << 12) | (unsigned)j);
                }
                if ((unsigned)X1 < 256u) {
                    int j = gb[rowoff + X1 + 1];
                    if (j >= 0) ins16(L, ((unsigned)d2s << 12) | (unsigned)j);
                }
            }
            merge16(L, c);
        }
    }
    unsigned mine = 0;
#pragma unroll
    for (int j = 0; j < 16; ++j)
        if (t == j) mine = c[j];
    int g = (b << 12) | (int)(mine & 4095u);
    float4 mef = *(const float4*)(xyzp + (size_t)q * 4);
    float4 tt = *(const float4*)(xyzp + (size_t)g * 4);
    float4 o;
    o.x = mef.x - tt.x; o.y = mef.y - tt.y; o.z = mef.w - tt.w;
    o.w = __int_as_float(g);
    relg[(size_t)q * 16 + t] = o;
}

// ---------------- weight pre-pack (+Wf/cf fold, +at_w1 folded into W2 q/k slices, +head weights) ----------------
#define PK128_SZ (4 * 8 * 512)
#define PKW1_SZ (9 * 3 * 8 * 512)
#define PKW2_SZ (9 * 4 * 24 * 512)
#define PKH_SZ 8192
#define PACK_TOTAL (3 * PK128_SZ + PKW1_SZ + PKW2_SZ + PK128_SZ + 128 + 3 * PKH_SZ)

__global__ __launch_bounds__(256) void k_pack(const float* __restrict__ pe_w2, const float* __restrict__ at_w1,
                                              const float* __restrict__ at_w2, const float* __restrict__ W1,
                                              const float* __restrict__ W2,
                                              const float* __restrict__ pe_b2, const float* __restrict__ at_b1,
                                              const float* __restrict__ ag_w, const float* __restrict__ mlp_w1,
                                              const float* __restrict__ mlp_w2,
                                              short* __restrict__ pk_pe2, short* __restrict__ pk_a1,
                                              short* __restrict__ pk_a2, short* __restrict__ pk_w1,
                                              short* __restrict__ pk_w2, short* __restrict__ pk_wf,
                                              float* __restrict__ cf, short* __restrict__ pk_ag,
                                              short* __restrict__ pk_m1, short* __restrict__ pk_m2) {
    int i = blockIdx.x * 256 + threadIdx.x;
    if (i < 3 * PK128_SZ) {
        int seg = i / PK128_SZ, r = i % PK128_SZ;
        int f = r / 512, q = r % 512;
        int lane = q / 8, j = q % 8;
        int kt = f / 8, nt = f % 8;
        int k = kt * 32 + (lane >> 4) * 8 + j, n = nt * 16 + (lane & 15);
        const float* W = (seg == 0) ? pe_w2 : (seg == 1) ? at_w1 : at_w2;
        short* dst = (seg == 0) ? pk_pe2 : (seg == 1) ? pk_a1 : pk_a2;
        dst[r] = f2b(W[k * 128 + n]);
        return;
    }
    i -= 3 * PK128_SZ;
    if (i < PKW1_SZ) {
        int f = i / 512, q = i % 512;
        int lane = q / 8, j = q % 8;
        int tap = f / 24, rem = f % 24;
        int kt = rem / 8, nt = rem % 8;
        int k = kt * 32 + (lane >> 4) * 8 + j, n = nt * 16 + (lane & 15);
        pk_w1[i] = (k < CIN) ? f2b(W1[(tap * CIN + k) * 128 + n]) : (short)0;
        return;
    }
    i -= PKW1_SZ;
    if (i < PKW2_SZ) {
        int f = i / 512, q = i % 512;
        int lane = q / 8, j = q % 8;
        int tap = f / 96, rem = f % 96;
        int kt = rem / 24, nt = rem % 24;
        int k = kt * 32 + (lane >> 4) * 8 + j, n = nt * 16 + (lane & 15);
        float acc;
        if (n < 256) {
            int sel = n >> 7, cc = n & 127;
            acc = 0.f;
            for (int m = 0; m < 128; ++m)
                acc += W2[((size_t)(tap * 128 + k)) * 384 + 3 * m + sel] * at_w1[m * 128 + cc];
        } else {
            acc = W2[((size_t)(tap * 128 + k)) * 384 + 3 * (n - 256) + 2];
        }
        pk_w2[i] = f2b(acc);
        return;
    }
    i -= PKW2_SZ;
    if (i < PK128_SZ) {
        int ii = i >> 7, j = i & 127;
        float acc = 0.f;
        for (int m = 0; m < 128; ++m) acc += pe_w2[ii * 128 + m] * at_w1[m * 128 + j];
        int lane = (((ii >> 3) & 3) << 4) | (j & 15);
        int dst = ((ii >> 5) * 8 + (j >> 4)) * 512 + lane * 8 + (ii & 7);
        pk_wf[dst] = f2b(acc);
        return;
    }
    i -= PK128_SZ;
    if (i < 128) {
        float acc = at_b1[i];
        for (int m = 0; m < 128; ++m) acc += pe_b2[m] * at_w1[m * 128 + i];
        cf[i] = acc;
        return;
    }
    i -= 128;
    if (i < PKH_SZ) {
        int f = i / 512, q = i % 512;
        int lane = q / 8, j = q % 8;
        int kt = f >> 2, nt = f & 3;
        int k = kt * 32 + (lane >> 4) * 8 + j, n = nt * 16 + (lane & 15);
        pk_ag[i] = f2b(ag_w[k * 64 + n]);
        return;
    }
    i -= PKH_SZ;
    if (i < PKH_SZ) {
        int f = i / 512, q = i % 512;
        int lane = q / 8, j = q % 8;
        int kt = f >> 3, nt = f & 7;
        int k = kt * 32 + (lane >> 4) * 8 + j, n = nt * 16 + (lane & 15);
        pk_m1[i] = f2b(mlp_w1[k * 128 + n]);
        return;
    }
    i -= PKH_SZ;
    if (i < PKH_SZ) {
        int f = i / 512, q = i % 512;
        int lane = q / 8, j = q % 8;
        int kt = f >> 2, nt = f & 3;
        int k = kt * 32 + (lane >> 4) * 8 + j, n = nt * 16 + (lane & 15);
        pk_m2[i] = f2b(mlp_w2[k * 64 + n]);
    }
}

// ---------------- conv1 (MFMA, 64-row blocks, DMA double-buffered) ----------------
__global__ __launch_bounds__(256, 4) void k_conv1(const int* __restrict__ grid, const int* __restrict__ cxy,
                                                  const short* __restrict__ sp_bf, const float* __restrict__ b1,
                                                  const short* __restrict__ pk_w1, const short* __restrict__ zero256,
                                                  short* __restrict__ h1_bf) {
    __shared__ int sj[9][64];
    __shared__ __align__(16) char sb[2][64 * 256];
    int row0 = blockIdx.x * 64;
    int b = row0 / NN;
    int tid = threadIdx.x;
    int w = tid >> 6, l = tid & 63, cl = l & 15;
    for (int e = tid; e < 9 * 64; e += 256) {
        int k = e / 64, p = e % 64;
        int me = cxy[row0 + p];
        sj[k][p] = grid[b * GS * GS + (((me >> 8) & 255) + k / 3) * GS + ((me & 255) + k % 3)];
    }
    __syncthreads();
    f32x4 acc[4][2];
#pragma unroll
    for (int m = 0; m < 4; m++)
#pragma unroll
        for (int nt = 0; nt < 2; nt++) acc[m][nt] = (f32x4){0.f, 0.f, 0.f, 0.f};

#define STAGE1(bufp, tap)                                                                      \
    {                                                                                          \
        _Pragma("unroll") for (int i = 0; i < 4; ++i) {                                        \
            int row = w * 16 + i * 4 + (l >> 4);                                               \
            int j = sj[tap][row];                                                              \
            int srcch = cl ^ (row & 7);                                                        \
            const short* src = (j >= 0) ? (sp_bf + ((size_t)(b * NN + j) * 128 + srcch * 8))   \
                                        : (zero256 + srcch * 8);                               \
            gload_lds16(src, (bufp) + (w * 16 + i * 4) * 256);                                 \
        }                                                                                      \
    }
    STAGE1(&sb[0][0], 0);
    asm volatile("s_waitcnt vmcnt(0)" ::: "memory");
    __syncthreads();
    int cur = 0;
    for (int tap = 0; tap < 9; ++tap) {
        if (tap < 8) STAGE1(&sb[cur ^ 1][0], tap + 1);
        const char* base = &sb[cur][0];
#pragma unroll
        for (int kt = 0; kt < 3; ++kt) {
            bf16x8 a[4];
#pragma unroll
            for (int m = 0; m < 4; ++m) {
                int row = m * 16 + (l & 15);
                a[m] = *(const bf16x8*)&base[row * 256 + ((kt * 64 + (l >> 4) * 16) ^ ((row & 7) << 4))];
            }
#pragma unroll
            for (int nt = 0; nt < 2; ++nt) {
                bf16x8 bv = *(const bf16x8*)(pk_w1 + (size_t)(((tap * 3 + kt) * 8 + w * 2 + nt) * 64 + l) * 8);
#pragma unroll
                for (int m = 0; m < 4; ++m) acc[m][nt] = MFMA_B16(a[m], bv, acc[m][nt]);
            }
        }
        asm volatile("s_waitcnt vmcnt(0)" ::: "memory");
        __syncthreads();
        cur ^= 1;
    }
#pragma unroll
    for (int nt = 0; nt < 2; ++nt) {
        int col = (w * 2 + nt) * 16 + cl;
        float bb = b1[col];
#pragma unroll
        for (int m = 0; m < 4; ++m)
#pragma unroll
            for (int j = 0; j < 4; ++j) {
                int row = row0 + m * 16 + (l >> 4) * 4 + j;
                h1_bf[(size_t)row * 128 + col] = f2b(acc[m][nt][j] + bb);
            }
    }
}

// ---------------- conv2 (folded): emits q1 (+cf), k1, v directly ----------------
__global__ __launch_bounds__(256, 4) void k_conv2(const int* __restrict__ grid, const int* __restrict__ cxy,
                                                  const short* __restrict__ h1_bf, const short* __restrict__ pk_w2,
                                                  const short* __restrict__ zero256, const float* __restrict__ cf,
                                                  short* __restrict__ q1, short* __restrict__ k1,
                                                  short* __restrict__ vg) {
    __shared__ int sj[9][64];
    __shared__ __align__(16) char sb[2][64 * 256];
    int bid = blockIdx.x;
    int nb = bid % 3, mb = bid / 3;
    int row0 = mb * 64;
    int b = row0 / NN;
    int tid = threadIdx.x;
    int w = tid >> 6, l = tid & 63, cl = l & 15;
    for (int e = tid; e < 9 * 64; e += 256) {
        int k = e / 64, p = e % 64;
        int me = cxy[row0 + p];
        sj[k][p] = grid[b * GS * GS + (((me >> 8) & 255) + k / 3) * GS + ((me & 255) + k % 3)];
    }
    __syncthreads();
    f32x4 acc[4][2];
#pragma unroll
    for (int m = 0; m < 4; m++)
#pragma unroll
        for (int nt = 0; nt < 2; nt++) acc[m][nt] = (f32x4){0.f, 0.f, 0.f, 0.f};

#define STAGE2(bufp, tap)                                                                      \
    {                                                                                          \
        _Pragma("unroll") for (int i = 0; i < 4; ++i) {                                        \
            int row = w * 16 + i * 4 + (l >> 4);                                               \
            int j = sj[tap][row];                                                              \
            int srcch = cl ^ (row & 7);                                                        \
            const short* src = (j >= 0) ? (h1_bf + ((size_t)(b * NN + j) * 128 + srcch * 8))   \
                                        : (zero256 + srcch * 8);                               \
            gload_lds16(src, (bufp) + (w * 16 + i * 4) * 256);                                 \
        }                                                                                      \
    }
    STAGE2(&sb[0][0], 0);
    asm volatile("s_waitcnt vmcnt(0)" ::: "memory");
    __syncthreads();
    int cur = 0;
    for (int tap = 0; tap < 9; ++tap) {
        if (tap < 8) STAGE2(&sb[cur ^ 1][0], tap + 1);
        const char* base = &sb[cur][0];
#pragma unroll
        for (int kt = 0; kt < 4; ++kt) {
            bf16x8 a[4];
#pragma unroll
            for (int m = 0; m < 4; ++m) {
                int row = m * 16 + (l & 15);
                a[m] = *(const bf16x8*)&base[row * 256 + ((kt * 64 + (l >> 4) * 16) ^ ((row & 7) << 4))];
            }
#pragma unroll
            for (int nt = 0; nt < 2; ++nt) {
                bf16x8 bv = *(const bf16x8*)(pk_w2 + (size_t)(((tap * 4 + kt) * 24 + nb * 8 + w * 2 + nt) * 64 + l) * 8);
#pragma unroll
                for (int m = 0; m < 4; ++m) acc[m][nt] = MFMA_B16(a[m], bv, acc[m][nt]);
            }
        }
        asm volatile("s_waitcnt vmcnt(0)" ::: "memory");
        __syncthreads();
        cur ^= 1;
    }
#pragma unroll
    for (int nt = 0; nt < 2; ++nt) {
        int col = nb * 128 + (w * 2 + nt) * 16 + cl;
        int seg = col >> 7, dd = col & 127;
        short* dst = (seg == 0) ? q1 : (seg == 1) ? k1 : vg;
        float cadd = (seg == 0) ? cf[dd] : 0.f;
#pragma unroll
        for (int m = 0; m < 4; ++m)
#pragma unroll
            for (int j = 0; j < 4; ++j) {
                int row = row0 + m * 16 + (l >> 4) * 4 + j;
                dst[(size_t)row * 128 + dd] = f2b(acc[m][nt][j] + cadd);
            }
    }
}

// ---------------- fused attention (launch_bounds(256,4): 128-reg budget >> 80 used, 50% occ ceiling) ----------------
__global__ __launch_bounds__(256, 4) void k_attn(const float4* __restrict__ relg,
                                                 const short* __restrict__ q1g, const short* __restrict__ k1g,
                                                 const short* __restrict__ vg,
                                                 const float* __restrict__ pe_w1, const float* __restrict__ pe_b1,
                                                 const float* __restrict__ pe_b2, const float* __restrict__ at_b2,
                                                 const short* __restrict__ pk_pe2, const short* __restrict__ pk_wf,
                                                 const short* __restrict__ pk_a2, short* __restrict__ res1b) {
    __shared__ __align__(16) char WK[64 * 256];
    __shared__ float4 s_rel[64];
    __shared__ int s_g[64];
    int tid = threadIdx.x;
    int w = tid >> 6, l = tid & 63, cl = l & 15;
    int P0 = blockIdx.x * 4;

    if (l < 16) {
        float4 f4 = relg[(size_t)(P0 + w) * 16 + l];
        s_rel[w * 16 + l] = f4;
        s_g[w * 16 + l] = __float_as_int(f4.w);
    }
    {
        int c0 = 2 * l;
        float wa0 = pe_w1[c0], wa1 = pe_w1[c0 + 1];
        float wb0 = pe_w1[128 + c0], wb1 = pe_w1[129 + c0];
        float wc0 = pe_w1[256 + c0], wc1 = pe_w1[257 + c0];
        float ba0 = pe_b1[c0], ba1 = pe_b1[c0 + 1];
#pragma unroll
        for (int lr = 0; lr < 16; ++lr) {
            float4 rel = s_rel[w * 16 + lr];
            float h0 = fmaxf(rel.x * wa0 + rel.y * wb0 + rel.z * wc0 + ba0, 0.f);
            float h1v = fmaxf(rel.x * wa1 + rel.y * wb1 + rel.z * wc1 + ba1, 0.f);
            *(unsigned*)&WK[(w * 16 + lr) * 256 + ((4 * l) ^ SWZ(lr))] = pk2(h0, h1v);
        }
    }
    __syncthreads();  // B1
    unsigned k1p[4][4];
    unsigned q1p[4];
#pragma unroll
    for (int m = 0; m < 4; ++m) {
#pragma unroll
        for (int j = 0; j < 4; ++j) {
            int g = s_g[m * 16 + (l >> 4) * 4 + j];
            unsigned lo = *((const unsigned short*)k1g + (size_t)g * 128 + w * 32 + cl);
            unsigned hi = *((const unsigned short*)k1g + (size_t)g * 128 + w * 32 + 16 + cl);
            k1p[m][j] = lo | (hi << 16);
        }
        unsigned qlo = *((const unsigned short*)q1g + (size_t)(P0 + m) * 128 + w * 32 + cl);
        unsigned qhi = *((const unsigned short*)q1g + (size_t)(P0 + m) * 128 + w * 32 + 16 + cl);
        q1p[m] = qlo | (qhi << 16);
    }
    unsigned pe_pk[4][2][2];
    {
        f32x4 pacc[4][2];
#pragma unroll
        for (int m = 0; m < 4; m++)
#pragma unroll
            for (int nt = 0; nt < 2; nt++) pacc[m][nt] = (f32x4){0.f, 0.f, 0.f, 0.f};
#pragma unroll
        for (int kt = 0; kt < 4; ++kt) {
            int off = kt * 64 + (l >> 4) * 16;
            bf16x8 a[4];
#pragma unroll
            for (int m = 0; m < 4; ++m) {
                int ra = m * 16 + (l & 15);
                a[m] = *(const bf16x8*)&WK[ra * 256 + (off ^ SWZ(ra))];
            }
#pragma unroll
            for (int nt = 0; nt < 2; ++nt) {
                bf16x8 bv = *(const bf16x8*)(pk_pe2 + (size_t)((kt * 8 + w * 2 + nt) * 64 + l) * 8);
#pragma unroll
                for (int m = 0; m < 4; ++m) pacc[m][nt] = MFMA_B16(a[m], bv, pacc[m][nt]);
            }
        }
#pragma unroll
        for (int nt = 0; nt < 2; ++nt) {
            float b2v = pe_b2[w * 32 + nt * 16 + cl];
#pragma unroll
            for (int m = 0; m < 4; ++m) {
                pe_pk[m][nt][0] = pk2(pacc[m][nt][0] + b2v, pacc[m][nt][1] + b2v);
                pe_pk[m][nt][1] = pk2(pacc[m][nt][2] + b2v, pacc[m][nt][3] + b2v);
            }
        }
    }
    f32x4 facc[4][2];
#pragma unroll
    for (int m = 0; m < 4; m++)
#pragma unroll
        for (int nt = 0; nt < 2; nt++) facc[m][nt] = (f32x4){0.f, 0.f, 0.f, 0.f};
#pragma unroll
    for (int kt = 0; kt < 4; ++kt) {
        int off = kt * 64 + (l >> 4) * 16;
        bf16x8 a[4];
#pragma unroll
        for (int m = 0; m < 4; ++m) {
            int ra = m * 16 + (l & 15);
            a[m] = *(const bf16x8*)&WK[ra * 256 + (off ^ SWZ(ra))];
        }
#pragma unroll
        for (int nt = 0; nt < 2; ++nt) {
            bf16x8 bv = *(const bf16x8*)(pk_wf + (size_t)((kt * 8 + w * 2 + nt) * 64 + l) * 8);
#pragma unroll
            for (int m = 0; m < 4; ++m) facc[m][nt] = MFMA_B16(a[m], bv, facc[m][nt]);
        }
    }
    __syncthreads();  // B2
#pragma unroll
    for (int m = 0; m < 4; ++m)
#pragma unroll
        for (int nt = 0; nt < 2; ++nt) {
            int col = w * 32 + nt * 16 + cl;
            float qv = b2f((short)((q1p[m] >> (nt * 16)) & 0xffff));
#pragma unroll
            for (int j = 0; j < 4; ++j) {
                int rr = m * 16 + (l >> 4) * 4 + j;
                float kv = b2f((short)((k1p[m][j] >> (nt * 16)) & 0xffff));
                float x = facc[m][nt][j] + qv - kv;
                *(short*)&WK[rr * 256 + ((col * 2) ^ SWZ(rr))] = f2b(fmaxf(x, 0.f));
            }
        }
    unsigned vp[4][4];
#pragma unroll
    for (int m = 0; m < 4; ++m)
#pragma unroll
        for (int j = 0; j < 4; ++j) {
            int g = s_g[m * 16 + (l >> 4) * 4 + j];
            unsigned lo = *((const unsigned short*)vg + (size_t)g * 128 + w * 32 + cl);
            unsigned hi = *((const unsigned short*)vg + (size_t)g * 128 + w * 32 + 16 + cl);
            vp[m][j] = lo | (hi << 16);
        }
    __syncthreads();  // B3
#pragma unroll
    for (int m = 0; m < 4; m++)
#pragma unroll
        for (int nt = 0; nt < 2; nt++) facc[m][nt] = (f32x4){0.f, 0.f, 0.f, 0.f};
#pragma unroll
    for (int kt = 0; kt < 4; ++kt) {
        int off = kt * 64 + (l >> 4) * 16;
        bf16x8 a[4];
#pragma unroll
        for (int m = 0; m < 4; ++m) {
            int ra = m * 16 + (l & 15);
            a[m] = *(const bf16x8*)&WK[ra * 256 + (off ^ SWZ(ra))];
        }
#pragma unroll
        for (int nt = 0; nt < 2; ++nt) {
            bf16x8 bv = *(const bf16x8*)(pk_a2 + (size_t)((kt * 8 + w * 2 + nt) * 64 + l) * 8);
#pragma unroll
            for (int m = 0; m < 4; ++m) facc[m][nt] = MFMA_B16(a[m], bv, facc[m][nt]);
        }
    }
    // max-free softmax in base 2 (softmax shift-invariance; scores bounded)
    const float scale2 = 0.08838834764831845f * 1.4426950408889634f;
#pragma unroll
    for (int m = 0; m < 4; ++m)
#pragma unroll
        for (int nt = 0; nt < 2; ++nt) {
            int col = w * 32 + nt * 16 + cl;
            float bv = at_b2[col];
            float ee[4], es = 0.f;
#pragma unroll
            for (int j = 0; j < 4; ++j) {
                ee[j] = exp2f((facc[m][nt][j] + bv) * scale2);
                es += ee[j];
            }
            es += __shfl_xor(es, 16);
            es += __shfl_xor(es, 32);
            float pev[4];
            pev[0] = b2f((short)(pe_pk[m][nt][0] & 0xffff));
            pev[1] = b2f((short)(pe_pk[m][nt][0] >> 16));
            pev[2] = b2f((short)(pe_pk[m][nt][1] & 0xffff));
            pev[3] = b2f((short)(pe_pk[m][nt][1] >> 16));
            float o = 0.f;
#pragma unroll
            for (int j = 0; j < 4; ++j) {
                float vvv = b2f((short)((vp[m][j] >> (nt * 16)) & 0xffff));
                o += ee[j] * (vvv + pev[j]);
            }
            o += __shfl_xor(o, 16);
            o += __shfl_xor(o, 32);
            if (l < 16) res1b[(size_t)(P0 + m) * 128 + col] = f2b(o / es);
        }
}

// ---------------- head (MFMA) ----------------
__global__ __launch_bounds__(256) void k_head(const short* __restrict__ res1b, const float* __restrict__ feat,
                                              const float* __restrict__ ag_b, const float* __restrict__ mlp_b1,
                                              const float* __restrict__ mlp_b2,
                                              const short* __restrict__ pk_ag, const short* __restrict__ pk_m1,
                                              const short* __restrict__ pk_m2, float* __restrict__ out) {
    __shared__ __align__(16) char sA[64 * 256];
    __shared__ __align__(16) char r1s[64 * 128];
    int tid = threadIdx.x;
    int w = tid >> 6, l = tid & 63, cl = l & 15;
    int i0 = blockIdx.x * 64;
    for (int e = tid; e < 1024; e += 256) {
        int row = e >> 4, sl = e & 15;
        gload_lds16(res1b + ((size_t)(i0 + row) * 128 + (sl ^ (row & 7)) * 8), &sA[e * 16]);
    }
    asm volatile("s_waitcnt vmcnt(0)" ::: "memory");
    __syncthreads();
    {
        f32x4 acc[4];
#pragma unroll
        for (int m = 0; m < 4; m++) acc[m] = (f32x4){0.f, 0.f, 0.f, 0.f};
#pragma unroll
        for (int kt = 0; kt < 4; ++kt) {
            bf16x8 a[4];
#pragma unroll
            for (int m = 0; m < 4; ++m) {
                int row = m * 16 + (l & 15);
                a[m] = *(const bf16x8*)&sA[row * 256 + ((kt * 64 + (l >> 4) * 16) ^ ((row & 7) << 4))];
            }
            bf16x8 bv = *(const bf16x8*)(pk_ag + (size_t)((kt * 4 + w) * 64 + l) * 8);
#pragma unroll
            for (int m = 0; m < 4; ++m) acc[m] = MFMA_B16(a[m], bv, acc[m]);
        }
        int col = w * 16 + cl;
        float bb = ag_b[col];
#pragma unroll
        for (int m = 0; m < 4; ++m)
#pragma unroll
            for (int j = 0; j < 4; ++j) {
                int row = m * 16 + (l >> 4) * 4 + j;
                float val = acc[m][j] + bb + feat[(size_t)(i0 + row) * 64 + col];
                *(short*)&r1s[row * 128 + ((col * 2) ^ ((row & 7) << 4))] = f2b(val);
            }
    }
    __syncthreads();
    {
        f32x4 acc[4][2];
#pragma unroll
        for (int m = 0; m < 4; m++)
#pragma unroll
            for (int nt = 0; nt < 2; nt++) acc[m][nt] = (f32x4){0.f, 0.f, 0.f, 0.f};
#pragma unroll
        for (int kt = 0; kt < 2; ++kt) {
            bf16x8 a[4];
#pragma unroll
            for (int m = 0; m < 4; ++m) {
                int row = m * 16 + (l & 15);
                a[m] = *(const bf16x8*)&r1s[row * 128 + ((kt * 64 + (l >> 4) * 16) ^ ((row & 7) << 4))];
            }
#pragma unroll
            for (int nt = 0; nt < 2; ++nt) {
                bf16x8 bv = *(const bf16x8*)(pk_m1 + (size_t)((kt * 8 + w * 2 + nt) * 64 + l) * 8);
#pragma unroll
                for (int m = 0; m < 4; ++m) acc[m][nt] = MFMA_B16(a[m], bv, acc[m][nt]);
            }
        }
#pragma unroll
        for (int nt = 0; nt < 2; ++nt) {
            int col = (w * 2 + nt) * 16 + cl;
            float bb = mlp_b1[col];
#pragma unroll
            for (int m = 0; m < 4; ++m)
#pragma unroll
                for (int j = 0; j < 4; ++j) {
                    int row = m * 16 + (l >> 4) * 4 + j;
                    float x = acc[m][nt][j] + bb;
                    float g = 0.5f * x * (1.0f + erff(x * 0.70710678118654752f));
                    *(short*)&sA[row * 256 + ((col * 2) ^ ((row & 7) << 4))] = f2b(g);
                }
        }
    }
    __syncthreads();
    {
        f32x4 acc[4];
#pragma unroll
        for (int m = 0; m < 4; m++) acc[m] = (f32x4){0.f, 0.f, 0.f, 0.f};
#pragma unroll
        for (int kt = 0; kt < 4; ++kt) {
            bf16x8 a[4];
#pragma unroll
            for (int m = 0; m < 4; ++m) {
                int row = m * 16 + (l & 15);
                a[m] = *(const bf16x8*)&sA[row * 256 + ((kt * 64 + (l >> 4) * 16) ^ ((row & 7) << 4))];
            }
            bf16x8 bv = *(const bf16x8*)(pk_m2 + (size_t)((kt * 4 + w) * 64 + l) * 8);
#pragma unroll
            for (int m = 0; m < 4; ++m) acc[m] = MFMA_B16(a[m], bv, acc[m]);
        }
        int col = w * 16 + cl;
        float bb = mlp_b2[col];
#pragma unroll
        for (int m = 0; m < 4; ++m)
#pragma unroll
            for (int j = 0; j < 4; ++j) {
                int row = m * 16 + (l >> 4) * 4 + j;
                out[(size_t)(i0 + row) * 64 + col] = acc[m][j] + bb + feat[(size_t)(i0 + row) * 64 + col];
            }
    }
}

extern "C" void kernel_launch(void* const* d_in, const int* in_sizes, int n_in,
                              void* d_out, int out_size, void* d_ws, size_t ws_size,
                              hipStream_t stream) {
    const float* xyzp = (const float*)d_in[0];
    const float* features = (const float*)d_in[1];
    const float* ln_g = (const float*)d_in[2];
    const float* ln_b = (const float*)d_in[3];
    const float* W1 = (const float*)d_in[4];
    const float* b1 = (const float*)d_in[5];
    const float* W2 = (const float*)d_in[6];
    const float* pe_w1 = (const float*)d_in[7];
    const float* pe_b1 = (const float*)d_in[8];
    const float* pe_w2 = (const float*)d_in[9];
    const float* pe_b2 = (const float*)d_in[10];
    const float* at_w1 = (const float*)d_in[11];
    const float* at_b1 = (const float*)d_in[12];
    const float* at_w2 = (const float*)d_in[13];
    const float* at_b2 = (const float*)d_in[14];
    const float* ag_w = (const float*)d_in[15];
    const float* ag_b = (const float*)d_in[16];
    const float* mlp_w1 = (const float*)d_in[17];
    const float* mlp_b1 = (const float*)d_in[18];
    const float* mlp_w2 = (const float*)d_in[19];
    const float* mlp_b2 = (const float*)d_in[20];
    float* out = (float*)d_out;

    char* w = (char*)d_ws;
    auto alloc = [&](size_t bytes) { char* pp = w; w += (bytes + 255) & ~(size_t)255; return pp; };
    int* grid = (int*)alloc((size_t)BB * GS * GS * 4);
    short* zero256 = (short*)alloc(256);
    int* cxy = (int*)alloc((size_t)BB * NN * 4);
    float4* relg = (float4*)alloc((size_t)BB * NN * KNN * 16);
    short* sp_bf = (short*)alloc((size_t)BB * NN * 128 * 2);
    short* h1_bf = (short*)alloc((size_t)BB * NN * HID * 2);
    short* q1 = (short*)alloc((size_t)BB * NN * HID * 2);
    short* k1 = (short*)alloc((size_t)BB * NN * HID * 2);
    short* vg = (short*)alloc((size_t)BB * NN * HID * 2);
    short* res1b = (short*)alloc((size_t)BB * NN * HID * 2);
    short* pk_pe2 = (short*)alloc((size_t)PK128_SZ * 2);
    short* pk_a1 = (short*)alloc((size_t)PK128_SZ * 2);
    short* pk_a2 = (short*)alloc((size_t)PK128_SZ * 2);
    short* pk_wf = (short*)alloc((size_t)PK128_SZ * 2);
    short* pk_w1 = (short*)alloc((size_t)PKW1_SZ * 2);
    short* pk_w2 = (short*)alloc((size_t)PKW2_SZ * 2);
    short* pk_ag = (short*)alloc((size_t)PKH_SZ * 2);
    short* pk_m1 = (short*)alloc((size_t)PKH_SZ * 2);
    short* pk_m2 = (short*)alloc((size_t)PKH_SZ * 2);
    float* cf = (float*)alloc(128 * 4);

    hipMemsetAsync(grid, 0xFF, (size_t)BB * GS * GS * 4, stream);
    hipMemsetAsync(zero256, 0, 256, stream);
    k_scatter_sp<<<(BB * NN + 255) / 256, 256, 0, stream>>>(xyzp, features, ln_g, ln_b, grid, cxy, sp_bf);
    k_pack<<<(PACK_TOTAL + 255) / 256, 256, 0, stream>>>(
        pe_w2, at_w1, at_w2, W1, W2, pe_b2, at_b1, ag_w, mlp_w1, mlp_w2,
        pk_pe2, pk_a1, pk_a2, pk_w1, pk_w2, pk_wf, cf, pk_ag, pk_m1, pk_m2);
    k_knn<<<BB * NN / 16, 256, 0, stream>>>(grid, cxy, xyzp, relg);
    k_conv1<<<BB * NN / 64, 256, 0, stream>>>(grid, cxy, sp_bf, b1, pk_w1, zero256, h1_bf);
    k_conv2<<<(BB * NN / 64) * 3, 256, 0, stream>>>(grid, cxy, h1_bf, pk_w2, zero256, cf, q1, k1, vg);
    k_attn<<<BB * NN / 4, 256, 0, stream>>>(relg, q1, k1, vg, pe_w1, pe_b1, pe_b2, at_b2,
                                            pk_pe2, pk_wf, pk_a2, res1b);
    k_head<<<BB * NN / 64, 256, 0, stream>>>(res1b, features, ag_b, mlp_b1, mlp_b2, pk_ag, pk_m1, pk_m2, out);
}

// Round 19
// 205.625 us; speedup vs baseline: 1.4266x; 1.0775x over previous
//
#include <hip/hip_runtime.h>
#include <hip/hip_bf16.h>
#include <math.h>

#define BB 4
#define NN 4096
#define FEAT 64
#define HID 128
#define KNN 16
#define GS 258
#define CIN 66

typedef __attribute__((ext_vector_type(8))) short bf16x8;
typedef __attribute__((ext_vector_type(4))) float f32x4;
#define MFMA_B16(a, b, c) __builtin_amdgcn_mfma_f32_16x16x32_bf16(a, b, c, 0, 0, 0)
#define SWZ(r) ((((r) & 7) << 4) ^ (((r) & 8) << 2))

__device__ __forceinline__ short f2b(float f) {
    __hip_bfloat16 h = __float2bfloat16(f);
    return __builtin_bit_cast(short, h);
}
__device__ __forceinline__ unsigned pk2(float lo, float hi) {
    return (unsigned)(unsigned short)f2b(lo) | (((unsigned)(unsigned short)f2b(hi)) << 16);
}
__device__ __forceinline__ float b2f(short s) {
    return __builtin_bit_cast(float, ((unsigned)(unsigned short)s) << 16);
}
__device__ __forceinline__ void gload_lds16(const void* g, void* lds) {
    __builtin_amdgcn_global_load_lds((const __attribute__((address_space(1))) unsigned int*)g,
                                     (__attribute__((address_space(3))) unsigned int*)lds, 16, 0, 0);
}

// ---------------- fused scatter + LayerNorm->bf16 ----------------
__global__ __launch_bounds__(256) void k_scatter_sp(const float* __restrict__ xyzp, const float* __restrict__ feat,
                                                    const float* __restrict__ ln_g, const float* __restrict__ ln_b,
                                                    int* __restrict__ grid, int* __restrict__ cxy,
                                                    short* __restrict__ sp_bf) {
    int i = blockIdx.x * 256 + threadIdx.x;
    if (i >= BB * NN) return;
    int b = i / NN;
    float4 xp = *(const float4*)(xyzp + (size_t)i * 4);
    int cx = __float2int_rn(xp.x * 256.0f);
    int cy = __float2int_rn(xp.y * 256.0f);
    cxy[i] = cx | (cy << 8);
    grid[b * GS * GS + (cy + 1) * GS + (cx + 1)] = i % NN;
    float v[CIN];
    float pn = (xp.w - 0.5f) * 2.0f;
    v[0] = fminf(fmaxf(pn, 0.0f), 1.0f);
    v[1] = -fminf(fmaxf(pn, -1.0f), 0.0f);
    const float4* f4 = (const float4*)(feat + (size_t)i * FEAT);
#pragma unroll
    for (int j = 0; j < FEAT / 4; j++) {
        float4 t = f4[j];
        v[2 + 4 * j] = t.x; v[3 + 4 * j] = t.y; v[4 + 4 * j] = t.z; v[5 + 4 * j] = t.w;
    }
    float s = 0.0f;
#pragma unroll
    for (int j = 0; j < CIN; j++) s += v[j];
    float mu = s / (float)CIN;
    float vs = 0.0f;
#pragma unroll
    for (int j = 0; j < CIN; j++) { float d = v[j] - mu; vs += d * d; }
    float inv = 1.0f / sqrtf(vs / (float)CIN + 1e-5f);
    unsigned o2[64];
#pragma unroll
    for (int j = 0; j < 33; j++) {
        float a = (v[2 * j] - mu) * inv * ln_g[2 * j] + ln_b[2 * j];
        float bqq = (2 * j + 1 < CIN) ? ((v[2 * j + 1] - mu) * inv * ln_g[2 * j + 1] + ln_b[2 * j + 1]) : 0.f;
        o2[j] = pk2(a, bqq);
    }
#pragma unroll
    for (int j = 33; j < 64; j++) o2[j] = 0;
    int4* o = (int4*)(sp_bf + (size_t)i * 128);
#pragma unroll
    for (int t = 0; t < 16; t++) o[t] = make_int4(o2[4 * t], o2[4 * t + 1], o2[4 * t + 2], o2[4 * t + 3]);
}

// ---------------- exact KNN ----------------
__device__ __forceinline__ void ins16(unsigned* a, unsigned key) {
    if (key < a[15]) {
#pragma unroll
        for (int j = 15; j >= 1; --j) {
            unsigned prev = a[j - 1];
            a[j] = (prev > key) ? prev : ((a[j] > key) ? key : a[j]);
        }
        a[0] = a[0] < key ? a[0] : key;
    }
}

__device__ __forceinline__ void cmpex(unsigned& x, unsigned& y) {
    unsigned lo = x < y ? x : y;
    unsigned hi = x < y ? y : x;
    x = lo; y = hi;
}

__device__ __forceinline__ void merge16(const unsigned* L, unsigned* c) {
#pragma unroll
    for (int i = 0; i < 16; ++i) c[i] = L[i];
#pragma unroll
    for (int s = 0; s < 4; ++s) {
        int m = 1 << s;
        unsigned bv[16];
#pragma unroll
        for (int i = 0; i < 16; ++i) bv[i] = __shfl_xor(c[15 - i], m);
#pragma unroll
        for (int i = 0; i < 16; ++i) c[i] = c[i] < bv[i] ? c[i] : bv[i];
#pragma unroll
        for (int d = 8; d >= 1; d >>= 1)
#pragma unroll
            for (int i = 0; i < 16; ++i)
                if (!(i & d)) cmpex(c[i], c[i | d]);
    }
}

__global__ __launch_bounds__(256) void k_knn(const int* __restrict__ grid, const int* __restrict__ cxy,
                                             const float* __restrict__ xyzp, float4* __restrict__ relg) {
    int tid = threadIdx.x;
    int t = tid & 15;
    int q = blockIdx.x * 16 + (tid >> 4);
    int b = q >> 12;
    int me = cxy[q];
    int mx = me & 255, my = (me >> 8) & 255;
    const int* gb = grid + b * GS * GS;
    unsigned L[16];
#pragma unroll
    for (int j = 0; j < 16; j++) L[j] = 0xFFFFFFFFu;
    for (int i = t; i < 441; i += 16) {
        int dy = i / 21 - 10, dx = i % 21 - 10;
        int Y = my + dy, X = mx + dx;
        if ((unsigned)Y >= 256u || (unsigned)X >= 256u) continue;
        int j = gb[(Y + 1) * GS + X + 1];
        if (j >= 0) ins16(L, ((unsigned)(dx * dx + dy * dy) << 12) | (unsigned)j);
    }
    unsigned c[16];
    merge16(L, c);
    for (int r = 11; r <= 256; ++r) {
        bool need = (c[15] >> 12) >= (unsigned)(r * r);
        if (!__any(need)) break;
        if (need) {
            int rr = r * r;
            for (int dx = -r + t; dx <= r; dx += 16) {
                int X = mx + dx;
                if ((unsigned)X >= 256u) continue;
                int d2t = dx * dx + rr;
                int Y0 = my - r, Y1 = my + r;
                if ((unsigned)Y0 < 256u) {
                    int j = gb[(Y0 + 1) * GS + X + 1];
                    if (j >= 0) ins16(L, ((unsigned)d2t << 12) | (unsigned)j);
                }
                if ((unsigned)Y1 < 256u) {
                    int j = gb[(Y1 + 1) * GS + X + 1];
                    if (j >= 0) ins16(L, ((unsigned)d2t << 12) | (unsigned)j);
                }
            }
            for (int dy = -r + 1 + t; dy <= r - 1; dy += 16) {
                int Y = my + dy;
                if ((unsigned)Y >= 256u) continue;
                int rowoff = (Y + 1) * GS;
                int d2s = rr + dy * dy;
                int X0 = mx - r, X1 = mx + r;
                if ((unsigned)X0 < 256u) {
                    int j = gb[rowoff + X0 + 1];
                    if (j >= 0) ins16(L, ((unsigned)d2s << 12) | (unsigned)j);
                }
                if ((unsigned)X1 < 256u) {
                    int j = gb[rowoff + X1 + 1];
                    if (j >= 0) ins16(L, ((unsigned)d2s << 12) | (unsigned)j);
                }
            }
            merge16(L, c);
        }
    }
    unsigned mine = 0;
#pragma unroll
    for (int j = 0; j < 16; ++j)
        if (t == j) mine = c[j];
    int g = (b << 12) | (int)(mine & 4095u);
    float4 mef = *(const float4*)(xyzp + (size_t)q * 4);
    float4 tt = *(const float4*)(xyzp + (size_t)g * 4);
    float4 o;
    o.x = mef.x - tt.x; o.y = mef.y - tt.y; o.z = mef.w - tt.w;
    o.w = __int_as_float(g);
    relg[(size_t)q * 16 + t] = o;
}

// ---------------- weight pre-pack (+Wf/cf fold, +at_w1 folded into W2 q/k slices, +head weights) ----------------
#define PK128_SZ (4 * 8 * 512)
#define PKW1_SZ (9 * 3 * 8 * 512)
#define PKW2_SZ (9 * 4 * 24 * 512)
#define PKH_SZ 8192
#define PACK_TOTAL (3 * PK128_SZ + PKW1_SZ + PKW2_SZ + PK128_SZ + 128 + 3 * PKH_SZ)

__global__ __launch_bounds__(256) void k_pack(const float* __restrict__ pe_w2, const float* __restrict__ at_w1,
                                              const float* __restrict__ at_w2, const float* __restrict__ W1,
                                              const float* __restrict__ W2,
                                              const float* __restrict__ pe_b2, const float* __restrict__ at_b1,
                                              const float* __restrict__ ag_w, const float* __restrict__ mlp_w1,
                                              const float* __restrict__ mlp_w2,
                                              short* __restrict__ pk_pe2, short* __restrict__ pk_a1,
                                              short* __restrict__ pk_a2, short* __restrict__ pk_w1,
                                              short* __restrict__ pk_w2, short* __restrict__ pk_wf,
                                              float* __restrict__ cf, short* __restrict__ pk_ag,
                                              short* __restrict__ pk_m1, short* __restrict__ pk_m2) {
    int i = blockIdx.x * 256 + threadIdx.x;
    if (i < 3 * PK128_SZ) {
        int seg = i / PK128_SZ, r = i % PK128_SZ;
        int f = r / 512, q = r % 512;
        int lane = q / 8, j = q % 8;
        int kt = f / 8, nt = f % 8;
        int k = kt * 32 + (lane >> 4) * 8 + j, n = nt * 16 + (lane & 15);
        const float* W = (seg == 0) ? pe_w2 : (seg == 1) ? at_w1 : at_w2;
        short* dst = (seg == 0) ? pk_pe2 : (seg == 1) ? pk_a1 : pk_a2;
        dst[r] = f2b(W[k * 128 + n]);
        return;
    }
    i -= 3 * PK128_SZ;
    if (i < PKW1_SZ) {
        int f = i / 512, q = i % 512;
        int lane = q / 8, j = q % 8;
        int tap = f / 24, rem = f % 24;
        int kt = rem / 8, nt = rem % 8;
        int k = kt * 32 + (lane >> 4) * 8 + j, n = nt * 16 + (lane & 15);
        pk_w1[i] = (k < CIN) ? f2b(W1[(tap * CIN + k) * 128 + n]) : (short)0;
        return;
    }
    i -= PKW1_SZ;
    if (i < PKW2_SZ) {
        int f = i / 512, q = i % 512;
        int lane = q / 8, j = q % 8;
        int tap = f / 96, rem = f % 96;
        int kt = rem / 24, nt = rem % 24;
        int k = kt * 32 + (lane >> 4) * 8 + j, n = nt * 16 + (lane & 15);
        float acc;
        if (n < 256) {
            int sel = n >> 7, cc = n & 127;
            const float* wrow = W2 + ((size_t)(tap * 128 + k)) * 384 + sel;
            float a0 = 0.f, a1 = 0.f, a2 = 0.f, a3 = 0.f;
#pragma unroll 4
            for (int m = 0; m < 128; m += 4) {
                a0 += wrow[3 * m] * at_w1[m * 128 + cc];
                a1 += wrow[3 * (m + 1)] * at_w1[(m + 1) * 128 + cc];
                a2 += wrow[3 * (m + 2)] * at_w1[(m + 2) * 128 + cc];
                a3 += wrow[3 * (m + 3)] * at_w1[(m + 3) * 128 + cc];
            }
            acc = (a0 + a1) + (a2 + a3);
        } else {
            acc = W2[((size_t)(tap * 128 + k)) * 384 + 3 * (n - 256) + 2];
        }
        pk_w2[i] = f2b(acc);
        return;
    }
    i -= PKW2_SZ;
    if (i < PK128_SZ) {
        int ii = i >> 7, j = i & 127;
        float a0 = 0.f, a1 = 0.f, a2 = 0.f, a3 = 0.f;
#pragma unroll 4
        for (int m = 0; m < 128; m += 4) {
            a0 += pe_w2[ii * 128 + m] * at_w1[m * 128 + j];
            a1 += pe_w2[ii * 128 + m + 1] * at_w1[(m + 1) * 128 + j];
            a2 += pe_w2[ii * 128 + m + 2] * at_w1[(m + 2) * 128 + j];
            a3 += pe_w2[ii * 128 + m + 3] * at_w1[(m + 3) * 128 + j];
        }
        float acc = (a0 + a1) + (a2 + a3);
        int lane = (((ii >> 3) & 3) << 4) | (j & 15);
        int dst = ((ii >> 5) * 8 + (j >> 4)) * 512 + lane * 8 + (ii & 7);
        pk_wf[dst] = f2b(acc);
        return;
    }
    i -= PK128_SZ;
    if (i < 128) {
        float a0 = at_b1[i], a1 = 0.f, a2 = 0.f, a3 = 0.f;
#pragma unroll 4
        for (int m = 0; m < 128; m += 4) {
            a0 += pe_b2[m] * at_w1[m * 128 + i];
            a1 += pe_b2[m + 1] * at_w1[(m + 1) * 128 + i];
            a2 += pe_b2[m + 2] * at_w1[(m + 2) * 128 + i];
            a3 += pe_b2[m + 3] * at_w1[(m + 3) * 128 + i];
        }
        cf[i] = (a0 + a1) + (a2 + a3);
        return;
    }
    i -= 128;
    if (i < PKH_SZ) {
        int f = i / 512, q = i % 512;
        int lane = q / 8, j = q % 8;
        int kt = f >> 2, nt = f & 3;
        int k = kt * 32 + (lane >> 4) * 8 + j, n = nt * 16 + (lane & 15);
        pk_ag[i] = f2b(ag_w[k * 64 + n]);
        return;
    }
    i -= PKH_SZ;
    if (i < PKH_SZ) {
        int f = i / 512, q = i % 512;
        int lane = q / 8, j = q % 8;
        int kt = f >> 3, nt = f & 7;
        int k = kt * 32 + (lane >> 4) * 8 + j, n = nt * 16 + (lane & 15);
        pk_m1[i] = f2b(mlp_w1[k * 128 + n]);
        return;
    }
    i -= PKH_SZ;
    if (i < PKH_SZ) {
        int f = i / 512, q = i % 512;
        int lane = q / 8, j = q % 8;
        int kt = f >> 2, nt = f & 3;
        int k = kt * 32 + (lane >> 4) * 8 + j, n = nt * 16 + (lane & 15);
        pk_m2[i] = f2b(mlp_w2[k * 64 + n]);
    }
}

// ---------------- conv1 (MFMA, 64-row blocks, DMA double-buffered) ----------------
__global__ __launch_bounds__(256) void k_conv1(const int* __restrict__ grid, const int* __restrict__ cxy,
                                               const short* __restrict__ sp_bf, const float* __restrict__ b1,
                                               const short* __restrict__ pk_w1, const short* __restrict__ zero256,
                                               short* __restrict__ h1_bf) {
    __shared__ int sj[9][64];
    __shared__ __align__(16) char sb[2][64 * 256];
    int row0 = blockIdx.x * 64;
    int b = row0 / NN;
    int tid = threadIdx.x;
    int w = tid >> 6, l = tid & 63, cl = l & 15;
    for (int e = tid; e < 9 * 64; e += 256) {
        int k = e / 64, p = e % 64;
        int me = cxy[row0 + p];
        sj[k][p] = grid[b * GS * GS + (((me >> 8) & 255) + k / 3) * GS + ((me & 255) + k % 3)];
    }
    __syncthreads();
    f32x4 acc[4][2];
#pragma unroll
    for (int m = 0; m < 4; m++)
#pragma unroll
        for (int nt = 0; nt < 2; nt++) acc[m][nt] = (f32x4){0.f, 0.f, 0.f, 0.f};

#define STAGE1(bufp, tap)                                                                      \
    {                                                                                          \
        _Pragma("unroll") for (int i = 0; i < 4; ++i) {                                        \
            int row = w * 16 + i * 4 + (l >> 4);                                               \
            int j = sj[tap][row];                                                              \
            int srcch = cl ^ (row & 7);                                                        \
            const short* src = (j >= 0) ? (sp_bf + ((size_t)(b * NN + j) * 128 + srcch * 8))   \
                                        : (zero256 + srcch * 8);                               \
            gload_lds16(src, (bufp) + (w * 16 + i * 4) * 256);                                 \
        }                                                                                      \
    }
    STAGE1(&sb[0][0], 0);
    asm volatile("s_waitcnt vmcnt(0)" ::: "memory");
    __syncthreads();
    int cur = 0;
    for (int tap = 0; tap < 9; ++tap) {
        if (tap < 8) STAGE1(&sb[cur ^ 1][0], tap + 1);
        const char* base = &sb[cur][0];
#pragma unroll
        for (int kt = 0; kt < 3; ++kt) {
            bf16x8 a[4];
#pragma unroll
            for (int m = 0; m < 4; ++m) {
                int row = m * 16 + (l & 15);
                a[m] = *(const bf16x8*)&base[row * 256 + ((kt * 64 + (l >> 4) * 16) ^ ((row & 7) << 4))];
            }
#pragma unroll
            for (int nt = 0; nt < 2; ++nt) {
                bf16x8 bv = *(const bf16x8*)(pk_w1 + (size_t)(((tap * 3 + kt) * 8 + w * 2 + nt) * 64 + l) * 8);
#pragma unroll
                for (int m = 0; m < 4; ++m) acc[m][nt] = MFMA_B16(a[m], bv, acc[m][nt]);
            }
        }
        asm volatile("s_waitcnt vmcnt(0)" ::: "memory");
        __syncthreads();
        cur ^= 1;
    }
#pragma unroll
    for (int nt = 0; nt < 2; ++nt) {
        int col = (w * 2 + nt) * 16 + cl;
        float bb = b1[col];
#pragma unroll
        for (int m = 0; m < 4; ++m)
#pragma unroll
            for (int j = 0; j < 4; ++j) {
                int row = row0 + m * 16 + (l >> 4) * 4 + j;
                h1_bf[(size_t)row * 128 + col] = f2b(acc[m][nt][j] + bb);
            }
    }
}

// ---------------- conv2 (folded): emits q1 (+cf), k1, v directly ----------------
__global__ __launch_bounds__(256) void k_conv2(const int* __restrict__ grid, const int* __restrict__ cxy,
                                               const short* __restrict__ h1_bf, const short* __restrict__ pk_w2,
                                               const short* __restrict__ zero256, const float* __restrict__ cf,
                                               short* __restrict__ q1, short* __restrict__ k1, short* __restrict__ vg) {
    __shared__ int sj[9][64];
    __shared__ __align__(16) char sb[2][64 * 256];
    int bid = blockIdx.x;
    int nb = bid % 3, mb = bid / 3;
    int row0 = mb * 64;
    int b = row0 / NN;
    int tid = threadIdx.x;
    int w = tid >> 6, l = tid & 63, cl = l & 15;
    for (int e = tid; e < 9 * 64; e += 256) {
        int k = e / 64, p = e % 64;
        int me = cxy[row0 + p];
        sj[k][p] = grid[b * GS * GS + (((me >> 8) & 255) + k / 3) * GS + ((me & 255) + k % 3)];
    }
    __syncthreads();
    f32x4 acc[4][2];
#pragma unroll
    for (int m = 0; m < 4; m++)
#pragma unroll
        for (int nt = 0; nt < 2; nt++) acc[m][nt] = (f32x4){0.f, 0.f, 0.f, 0.f};

#define STAGE2(bufp, tap)                                                                      \
    {                                                                                          \
        _Pragma("unroll") for (int i = 0; i < 4; ++i) {                                        \
            int row = w * 16 + i * 4 + (l >> 4);                                               \
            int j = sj[tap][row];                                                              \
            int srcch = cl ^ (row & 7);                                                        \
            const short* src = (j >= 0) ? (h1_bf + ((size_t)(b * NN + j) * 128 + srcch * 8))   \
                                        : (zero256 + srcch * 8);                               \
            gload_lds16(src, (bufp) + (w * 16 + i * 4) * 256);                                 \
        }                                                                                      \
    }
    STAGE2(&sb[0][0], 0);
    asm volatile("s_waitcnt vmcnt(0)" ::: "memory");
    __syncthreads();
    int cur = 0;
    for (int tap = 0; tap < 9; ++tap) {
        if (tap < 8) STAGE2(&sb[cur ^ 1][0], tap + 1);
        const char* base = &sb[cur][0];
#pragma unroll
        for (int kt = 0; kt < 4; ++kt) {
            bf16x8 a[4];
#pragma unroll
            for (int m = 0; m < 4; ++m) {
                int row = m * 16 + (l & 15);
                a[m] = *(const bf16x8*)&base[row * 256 + ((kt * 64 + (l >> 4) * 16) ^ ((row & 7) << 4))];
            }
#pragma unroll
            for (int nt = 0; nt < 2; ++nt) {
                bf16x8 bv = *(const bf16x8*)(pk_w2 + (size_t)(((tap * 4 + kt) * 24 + nb * 8 + w * 2 + nt) * 64 + l) * 8);
#pragma unroll
                for (int m = 0; m < 4; ++m) acc[m][nt] = MFMA_B16(a[m], bv, acc[m][nt]);
            }
        }
        asm volatile("s_waitcnt vmcnt(0)" ::: "memory");
        __syncthreads();
        cur ^= 1;
    }
#pragma unroll
    for (int nt = 0; nt < 2; ++nt) {
        int col = nb * 128 + (w * 2 + nt) * 16 + cl;
        int seg = col >> 7, dd = col & 127;
        short* dst = (seg == 0) ? q1 : (seg == 1) ? k1 : vg;
        float cadd = (seg == 0) ? cf[dd] : 0.f;
#pragma unroll
        for (int m = 0; m < 4; ++m)
#pragma unroll
            for (int j = 0; j < 4; ++j) {
                int row = row0 + m * 16 + (l >> 4) * 4 + j;
                dst[(size_t)row * 128 + dd] = f2b(acc[m][nt][j] + cadd);
            }
    }
}

// ---------------- fused attention (launch_bounds(256,3): the only non-spilling config) ----------------
__global__ __launch_bounds__(256, 3) void k_attn(const float4* __restrict__ relg,
                                                 const short* __restrict__ q1g, const short* __restrict__ k1g,
                                                 const short* __restrict__ vg,
                                                 const float* __restrict__ pe_w1, const float* __restrict__ pe_b1,
                                                 const float* __restrict__ pe_b2, const float* __restrict__ at_b2,
                                                 const short* __restrict__ pk_pe2, const short* __restrict__ pk_wf,
                                                 const short* __restrict__ pk_a2, short* __restrict__ res1b) {
    __shared__ __align__(16) char WK[64 * 256];
    __shared__ float4 s_rel[64];
    __shared__ int s_g[64];
    int tid = threadIdx.x;
    int w = tid >> 6, l = tid & 63, cl = l & 15;
    int P0 = blockIdx.x * 4;

    if (l < 16) {
        float4 f4 = relg[(size_t)(P0 + w) * 16 + l];
        s_rel[w * 16 + l] = f4;
        s_g[w * 16 + l] = __float_as_int(f4.w);
    }
    {
        int c0 = 2 * l;
        float wa0 = pe_w1[c0], wa1 = pe_w1[c0 + 1];
        float wb0 = pe_w1[128 + c0], wb1 = pe_w1[129 + c0];
        float wc0 = pe_w1[256 + c0], wc1 = pe_w1[257 + c0];
        float ba0 = pe_b1[c0], ba1 = pe_b1[c0 + 1];
#pragma unroll
        for (int lr = 0; lr < 16; ++lr) {
            float4 rel = s_rel[w * 16 + lr];
            float h0 = fmaxf(rel.x * wa0 + rel.y * wb0 + rel.z * wc0 + ba0, 0.f);
            float h1v = fmaxf(rel.x * wa1 + rel.y * wb1 + rel.z * wc1 + ba1, 0.f);
            *(unsigned*)&WK[(w * 16 + lr) * 256 + ((4 * l) ^ SWZ(lr))] = pk2(h0, h1v);
        }
    }
    __syncthreads();  // B1
    unsigned k1p[4][4];
    unsigned q1p[4];
#pragma unroll
    for (int m = 0; m < 4; ++m) {
#pragma unroll
        for (int j = 0; j < 4; ++j) {
            int g = s_g[m * 16 + (l >> 4) * 4 + j];
            unsigned lo = *((const unsigned short*)k1g + (size_t)g * 128 + w * 32 + cl);
            unsigned hi = *((const unsigned short*)k1g + (size_t)g * 128 + w * 32 + 16 + cl);
            k1p[m][j] = lo | (hi << 16);
        }
        unsigned qlo = *((const unsigned short*)q1g + (size_t)(P0 + m) * 128 + w * 32 + cl);
        unsigned qhi = *((const unsigned short*)q1g + (size_t)(P0 + m) * 128 + w * 32 + 16 + cl);
        q1p[m] = qlo | (qhi << 16);
    }
    unsigned pe_pk[4][2][2];
    {
        f32x4 pacc[4][2];
#pragma unroll
        for (int m = 0; m < 4; m++)
#pragma unroll
            for (int nt = 0; nt < 2; nt++) pacc[m][nt] = (f32x4){0.f, 0.f, 0.f, 0.f};
#pragma unroll
        for (int kt = 0; kt < 4; ++kt) {
            int off = kt * 64 + (l >> 4) * 16;
            bf16x8 a[4];
#pragma unroll
            for (int m = 0; m < 4; ++m) {
                int ra = m * 16 + (l & 15);
                a[m] = *(const bf16x8*)&WK[ra * 256 + (off ^ SWZ(ra))];
            }
#pragma unroll
            for (int nt = 0; nt < 2; ++nt) {
                bf16x8 bv = *(const bf16x8*)(pk_pe2 + (size_t)((kt * 8 + w * 2 + nt) * 64 + l) * 8);
#pragma unroll
                for (int m = 0; m < 4; ++m) pacc[m][nt] = MFMA_B16(a[m], bv, pacc[m][nt]);
            }
        }
#pragma unroll
        for (int nt = 0; nt < 2; ++nt) {
            float b2v = pe_b2[w * 32 + nt * 16 + cl];
#pragma unroll
            for (int m = 0; m < 4; ++m) {
                pe_pk[m][nt][0] = pk2(pacc[m][nt][0] + b2v, pacc[m][nt][1] + b2v);
                pe_pk[m][nt][1] = pk2(pacc[m][nt][2] + b2v, pacc[m][nt][3] + b2v);
            }
        }
    }
    f32x4 facc[4][2];
#pragma unroll
    for (int m = 0; m < 4; m++)
#pragma unroll
        for (int nt = 0; nt < 2; nt++) facc[m][nt] = (f32x4){0.f, 0.f, 0.f, 0.f};
#pragma unroll
    for (int kt = 0; kt < 4; ++kt) {
        int off = kt * 64 + (l >> 4) * 16;
        bf16x8 a[4];
#pragma unroll
        for (int m = 0; m < 4; ++m) {
            int ra = m * 16 + (l & 15);
            a[m] = *(const bf16x8*)&WK[ra * 256 + (off ^ SWZ(ra))];
        }
#pragma unroll
        for (int nt = 0; nt < 2; ++nt) {
            bf16x8 bv = *(const bf16x8*)(pk_wf + (size_t)((kt * 8 + w * 2 + nt) * 64 + l) * 8);
#pragma unroll
            for (int m = 0; m < 4; ++m) facc[m][nt] = MFMA_B16(a[m], bv, facc[m][nt]);
        }
    }
    __syncthreads();  // B2
#pragma unroll
    for (int m = 0; m < 4; ++m)
#pragma unroll
        for (int nt = 0; nt < 2; ++nt) {
            int col = w * 32 + nt * 16 + cl;
            float qv = b2f((short)((q1p[m] >> (nt * 16)) & 0xffff));
#pragma unroll
            for (int j = 0; j < 4; ++j) {
                int rr = m * 16 + (l >> 4) * 4 + j;
                float kv = b2f((short)((k1p[m][j] >> (nt * 16)) & 0xffff));
                float x = facc[m][nt][j] + qv - kv;
                *(short*)&WK[rr * 256 + ((col * 2) ^ SWZ(rr))] = f2b(fmaxf(x, 0.f));
            }
        }
    unsigned vp[4][4];
#pragma unroll
    for (int m = 0; m < 4; ++m)
#pragma unroll
        for (int j = 0; j < 4; ++j) {
            int g = s_g[m * 16 + (l >> 4) * 4 + j];
            unsigned lo = *((const unsigned short*)vg + (size_t)g * 128 + w * 32 + cl);
            unsigned hi = *((const unsigned short*)vg + (size_t)g * 128 + w * 32 + 16 + cl);
            vp[m][j] = lo | (hi << 16);
        }
    __syncthreads();  // B3
#pragma unroll
    for (int m = 0; m < 4; m++)
#pragma unroll
        for (int nt = 0; nt < 2; nt++) facc[m][nt] = (f32x4){0.f, 0.f, 0.f, 0.f};
#pragma unroll
    for (int kt = 0; kt < 4; ++kt) {
        int off = kt * 64 + (l >> 4) * 16;
        bf16x8 a[4];
#pragma unroll
        for (int m = 0; m < 4; ++m) {
            int ra = m * 16 + (l & 15);
            a[m] = *(const bf16x8*)&WK[ra * 256 + (off ^ SWZ(ra))];
        }
#pragma unroll
        for (int nt = 0; nt < 2; ++nt) {
            bf16x8 bv = *(const bf16x8*)(pk_a2 + (size_t)((kt * 8 + w * 2 + nt) * 64 + l) * 8);
#pragma unroll
            for (int m = 0; m < 4; ++m) facc[m][nt] = MFMA_B16(a[m], bv, facc[m][nt]);
        }
    }
    // max-free softmax in base 2 (softmax shift-invariance; scores bounded)
    const float scale2 = 0.08838834764831845f * 1.4426950408889634f;
#pragma unroll
    for (int m = 0; m < 4; ++m)
#pragma unroll
        for (int nt = 0; nt < 2; ++nt) {
            int col = w * 32 + nt * 16 + cl;
            float bv = at_b2[col];
            float ee[4], es = 0.f;
#pragma unroll
            for (int j = 0; j < 4; ++j) {
                ee[j] = exp2f((facc[m][nt][j] + bv) * scale2);
                es += ee[j];
            }
            es += __shfl_xor(es, 16);
            es += __shfl_xor(es, 32);
            float pev[4];
            pev[0] = b2f((short)(pe_pk[m][nt][0] & 0xffff));
            pev[1] = b2f((short)(pe_pk[m][nt][0] >> 16));
            pev[2] = b2f((short)(pe_pk[m][nt][1] & 0xffff));
            pev[3] = b2f((short)(pe_pk[m][nt][1] >> 16));
            float o = 0.f;
#pragma unroll
            for (int j = 0; j < 4; ++j) {
                float vvv = b2f((short)((vp[m][j] >> (nt * 16)) & 0xffff));
                o += ee[j] * (vvv + pev[j]);
            }
            o += __shfl_xor(o, 16);
            o += __shfl_xor(o, 32);
            if (l < 16) res1b[(size_t)(P0 + m) * 128 + col] = f2b(o / es);
        }
}

// ---------------- head (MFMA) ----------------
__global__ __launch_bounds__(256) void k_head(const short* __restrict__ res1b, const float* __restrict__ feat,
                                              const float* __restrict__ ag_b, const float* __restrict__ mlp_b1,
                                              const float* __restrict__ mlp_b2,
                                              const short* __restrict__ pk_ag, const short* __restrict__ pk_m1,
                                              const short* __restrict__ pk_m2, float* __restrict__ out) {
    __shared__ __align__(16) char sA[64 * 256];
    __shared__ __align__(16) char r1s[64 * 128];
    int tid = threadIdx.x;
    int w = tid >> 6, l = tid & 63, cl = l & 15;
    int i0 = blockIdx.x * 64;
    for (int e = tid; e < 1024; e += 256) {
        int row = e >> 4, sl = e & 15;
        gload_lds16(res1b + ((size_t)(i0 + row) * 128 + (sl ^ (row & 7)) * 8), &sA[e * 16]);
    }
    asm volatile("s_waitcnt vmcnt(0)" ::: "memory");
    __syncthreads();
    {
        f32x4 acc[4];
#pragma unroll
        for (int m = 0; m < 4; m++) acc[m] = (f32x4){0.f, 0.f, 0.f, 0.f};
#pragma unroll
        for (int kt = 0; kt < 4; ++kt) {
            bf16x8 a[4];
#pragma unroll
            for (int m = 0; m < 4; ++m) {
                int row = m * 16 + (l & 15);
                a[m] = *(const bf16x8*)&sA[row * 256 + ((kt * 64 + (l >> 4) * 16) ^ ((row & 7) << 4))];
            }
            bf16x8 bv = *(const bf16x8*)(pk_ag + (size_t)((kt * 4 + w) * 64 + l) * 8);
#pragma unroll
            for (int m = 0; m < 4; ++m) acc[m] = MFMA_B16(a[m], bv, acc[m]);
        }
        int col = w * 16 + cl;
        float bb = ag_b[col];
#pragma unroll
        for (int m = 0; m < 4; ++m)
#pragma unroll
            for (int j = 0; j < 4; ++j) {
                int row = m * 16 + (l >> 4) * 4 + j;
                float val = acc[m][j] + bb + feat[(size_t)(i0 + row) * 64 + col];
                *(short*)&r1s[row * 128 + ((col * 2) ^ ((row & 7) << 4))] = f2b(val);
            }
    }
    __syncthreads();
    {
        f32x4 acc[4][2];
#pragma unroll
        for (int m = 0; m < 4; m++)
#pragma unroll
            for (int nt = 0; nt < 2; nt++) acc[m][nt] = (f32x4){0.f, 0.f, 0.f, 0.f};
#pragma unroll
        for (int kt = 0; kt < 2; ++kt) {
            bf16x8 a[4];
#pragma unroll
            for (int m = 0; m < 4; ++m) {
                int row = m * 16 + (l & 15);
                a[m] = *(const bf16x8*)&r1s[row * 128 + ((kt * 64 + (l >> 4) * 16) ^ ((row & 7) << 4))];
            }
#pragma unroll
            for (int nt = 0; nt < 2; ++nt) {
                bf16x8 bv = *(const bf16x8*)(pk_m1 + (size_t)((kt * 8 + w * 2 + nt) * 64 + l) * 8);
#pragma unroll
                for (int m = 0; m < 4; ++m) acc[m][nt] = MFMA_B16(a[m], bv, acc[m][nt]);
            }
        }
#pragma unroll
        for (int nt = 0; nt < 2; ++nt) {
            int col = (w * 2 + nt) * 16 + cl;
            float bb = mlp_b1[col];
#pragma unroll
            for (int m = 0; m < 4; ++m)
#pragma unroll
                for (int j = 0; j < 4; ++j) {
                    int row = m * 16 + (l >> 4) * 4 + j;
                    float x = acc[m][nt][j] + bb;
                    float g = 0.5f * x * (1.0f + erff(x * 0.70710678118654752f));
                    *(short*)&sA[row * 256 + ((col * 2) ^ ((row & 7) << 4))] = f2b(g);
                }
        }
    }
    __syncthreads();
    {
        f32x4 acc[4];
#pragma unroll
        for (int m = 0; m < 4; m++) acc[m] = (f32x4){0.f, 0.f, 0.f, 0.f};
#pragma unroll
        for (int kt = 0; kt < 4; ++kt) {
            bf16x8 a[4];
#pragma unroll
            for (int m = 0; m < 4; ++m) {
                int row = m * 16 + (l & 15);
                a[m] = *(const bf16x8*)&sA[row * 256 + ((kt * 64 + (l >> 4) * 16) ^ ((row & 7) << 4))];
            }
            bf16x8 bv = *(const bf16x8*)(pk_m2 + (size_t)((kt * 4 + w) * 64 + l) * 8);
#pragma unroll
            for (int m = 0; m < 4; ++m) acc[m] = MFMA_B16(a[m], bv, acc[m]);
        }
        int col = w * 16 + cl;
        float bb = mlp_b2[col];
#pragma unroll
        for (int m = 0; m < 4; ++m)
#pragma unroll
            for (int j = 0; j < 4; ++j) {
                int row = m * 16 + (l >> 4) * 4 + j;
                out[(size_t)(i0 + row) * 64 + col] = acc[m][j] + bb + feat[(size_t)(i0 + row) * 64 + col];
            }
    }
}

extern "C" void kernel_launch(void* const* d_in, const int* in_sizes, int n_in,
                              void* d_out, int out_size, void* d_ws, size_t ws_size,
                              hipStream_t stream) {
    const float* xyzp = (const float*)d_in[0];
    const float* features = (const float*)d_in[1];
    const float* ln_g = (const float*)d_in[2];
    const float* ln_b = (const float*)d_in[3];
    const float* W1 = (const float*)d_in[4];
    const float* b1 = (const float*)d_in[5];
    const float* W2 = (const float*)d_in[6];
    const float* pe_w1 = (const float*)d_in[7];
    const float* pe_b1 = (const float*)d_in[8];
    const float* pe_w2 = (const float*)d_in[9];
    const float* pe_b2 = (const float*)d_in[10];
    const float* at_w1 = (const float*)d_in[11];
    const float* at_b1 = (const float*)d_in[12];
    const float* at_w2 = (const float*)d_in[13];
    const float* at_b2 = (const float*)d_in[14];
    const float* ag_w = (const float*)d_in[15];
    const float* ag_b = (const float*)d_in[16];
    const float* mlp_w1 = (const float*)d_in[17];
    const float* mlp_b1 = (const float*)d_in[18];
    const float* mlp_w2 = (const float*)d_in[19];
    const float* mlp_b2 = (const float*)d_in[20];
    float* out = (float*)d_out;

    char* w = (char*)d_ws;
    auto alloc = [&](size_t bytes) { char* pp = w; w += (bytes + 255) & ~(size_t)255; return pp; };
    int* grid = (int*)alloc((size_t)BB * GS * GS * 4);
    short* zero256 = (short*)alloc(256);
    int* cxy = (int*)alloc((size_t)BB * NN * 4);
    float4* relg = (float4*)alloc((size_t)BB * NN * KNN * 16);
    short* sp_bf = (short*)alloc((size_t)BB * NN * 128 * 2);
    short* h1_bf = (short*)alloc((size_t)BB * NN * HID * 2);
    short* q1 = (short*)alloc((size_t)BB * NN * HID * 2);
    short* k1 = (short*)alloc((size_t)BB * NN * HID * 2);
    short* vg = (short*)alloc((size_t)BB * NN * HID * 2);
    short* res1b = (short*)alloc((size_t)BB * NN * HID * 2);
    short* pk_pe2 = (short*)alloc((size_t)PK128_SZ * 2);
    short* pk_a1 = (short*)alloc((size_t)PK128_SZ * 2);
    short* pk_a2 = (short*)alloc((size_t)PK128_SZ * 2);
    short* pk_wf = (short*)alloc((size_t)PK128_SZ * 2);
    short* pk_w1 = (short*)alloc((size_t)PKW1_SZ * 2);
    short* pk_w2 = (short*)alloc((size_t)PKW2_SZ * 2);
    short* pk_ag = (short*)alloc((size_t)PKH_SZ * 2);
    short* pk_m1 = (short*)alloc((size_t)PKH_SZ * 2);
    short* pk_m2 = (short*)alloc((size_t)PKH_SZ * 2);
    float* cf = (float*)alloc(128 * 4);

    hipMemsetAsync(grid, 0xFF, (size_t)BB * GS * GS * 4, stream);
    hipMemsetAsync(zero256, 0, 256, stream);
    k_scatter_sp<<<(BB * NN + 255) / 256, 256, 0, stream>>>(xyzp, features, ln_g, ln_b, grid, cxy, sp_bf);
    k_pack<<<(PACK_TOTAL + 255) / 256, 256, 0, stream>>>(
        pe_w2, at_w1, at_w2, W1, W2, pe_b2, at_b1, ag_w, mlp_w1, mlp_w2,
        pk_pe2, pk_a1, pk_a2, pk_w1, pk_w2, pk_wf, cf, pk_ag, pk_m1, pk_m2);
    k_knn<<<BB * NN / 16, 256, 0, stream>>>(grid, cxy, xyzp, relg);
    k_conv1<<<BB * NN / 64, 256, 0, stream>>>(grid, cxy, sp_bf, b1, pk_w1, zero256, h1_bf);
    k_conv2<<<(BB * NN / 64) * 3, 256, 0, stream>>>(grid, cxy, h1_bf, pk_w2, zero256, cf, q1, k1, vg);
    k_attn<<<BB * NN / 4, 256, 0, stream>>>(relg, q1, k1, vg, pe_w1, pe_b1, pe_b2, at_b2,
                                            pk_pe2, pk_wf, pk_a2, res1b);
    k_head<<<BB * NN / 64, 256, 0, stream>>>(res1b, features, ag_b, mlp_b1, mlp_b2, pk_ag, pk_m1, pk_m2, out);
}